// Round 1
// baseline (3983.096 us; speedup 1.0000x reference)
//
#include <hip/hip_runtime.h>
#include <hip/hip_bf16.h>
#include <stdint.h>

typedef __hip_bfloat16 bf16;
typedef __attribute__((ext_vector_type(4))) int   i32x4;
typedef __attribute__((ext_vector_type(4))) float f32x4;

// Shapes (N=1): S=128, R=256, CM=256, CZ=128, C=32, MSA_H=8, PAIR_H=4, CTM=128, FF=4
// msa rows: s*256+r (32768 x 256); pair rows: i*256+j (65536 x 128)
// I/O dtype: FLOAT32. Accumulators f32 live directly in d_out (they ARE the outputs).
// Workspace (70 MB): weights 4MB | biasF 2MB | lnb 16MB | bufA 16MB | bufB 16MB | bufC 16MB.
// GEMM weights are staged TRANSPOSED (W^T [N][K]) so MFMA B-fragments read k-contiguous bf16x8.

__device__ __forceinline__ float toF(float x){ return x; }
__device__ __forceinline__ float toF(bf16 x){ return __bfloat162float(x); }
__device__ __forceinline__ bf16  toB(float x){ return __float2bfloat16(x); }

__device__ __forceinline__ void gload16(const bf16* g, bf16* l){
    __builtin_amdgcn_global_load_lds((const __attribute__((address_space(1))) void*)g,
                                     (__attribute__((address_space(3))) void*)l, 16, 0, 0);
}

// ---------------- input staging (dtype probe: bf16 ones -> 0x3F803F80, f32 one -> 0x3F800000) ----------------
__global__ void cvt_w_k(const void* __restrict__ in, bf16* __restrict__ out, int n,
                        const uint32_t* __restrict__ probe){
    bool isbf = (probe[0] == 0x3F803F80u);
    int i = blockIdx.x*256 + threadIdx.x;
    if (i < n) out[i] = isbf ? ((const bf16*)in)[i] : toB(((const float*)in)[i]);
}
// transpose-staging for GEMM B operands: in [K][N] row-major -> out [N][K] row-major
__global__ void cvt_wT_k(const void* __restrict__ in, bf16* __restrict__ out, int K, int N,
                         const uint32_t* __restrict__ probe){
    bool isbf = (probe[0] == 0x3F803F80u);
    int i = blockIdx.x*256 + threadIdx.x;
    if (i < K*N){
        float v = isbf ? toF(((const bf16*)in)[i]) : ((const float*)in)[i];
        int k = i / N, n = i - k*N;
        out[(size_t)n*K + k] = toB(v);
    }
}
__global__ void in2f_k(const void* __restrict__ in, float* __restrict__ out, int n,
                       const uint32_t* __restrict__ probe){
    bool isbf = (probe[0] == 0x3F803F80u);
    int i = blockIdx.x*256 + threadIdx.x;
    if (i < n) out[i] = isbf ? toF(((const bf16*)in)[i]) : ((const float*)in)[i];
}

// ---------------- LayerNorm: one block per row, blockDim = D (128 or 256); in-place safe ----------------
template<typename T>
__global__ void ln_k(const T* __restrict__ x, const bf16* __restrict__ w, const bf16* __restrict__ b,
                     bf16* __restrict__ out, int D){
    int row = blockIdx.x, c = threadIdx.x;
    float v = toF(x[(size_t)row*D + c]);
    float s1 = v, s2 = v*v;
    #pragma unroll
    for (int o=32;o>0;o>>=1){ s1 += __shfl_down(s1,o); s2 += __shfl_down(s2,o); }
    __shared__ float r1[4], r2[4];
    int lane = c & 63, wid = c >> 6;
    if (lane==0){ r1[wid]=s1; r2[wid]=s2; }
    __syncthreads();
    int nw = blockDim.x >> 6;
    float m=0.f, q=0.f;
    for (int i=0;i<nw;i++){ m+=r1[i]; q+=r2[i]; }
    m /= (float)D; q = q/(float)D - m*m;
    float inv = rsqrtf(q + 1e-5f);
    out[(size_t)row*D + c] = toB((v-m)*inv*toF(w[c]) + toF(b[c]));
}

// ---------------- fused LN + attention-bias projection (reads f32 pair acc) ----------------
// mode 0 (row attn, Hn=8): out[(h*256+j)*256+i]  ([h][k][q] layout -> lane-coalesced reads)
// mode 1 (tas, Hn=4):      out[(i*Hn+h)*256+j]
// mode 2 (tae, Hn=4):      out[(j*Hn+h)*256+i].  Value = dot(LN(pair[i,j]), Wb[:,h]).
__global__ void ln_bias_k(const float* __restrict__ pairf, const bf16* __restrict__ w, const bf16* __restrict__ b,
                          const bf16* __restrict__ Wb, float* __restrict__ outb, int Hn, int mode){
    int pp = blockIdx.x, c = threadIdx.x;           // 128 threads
    int i = pp >> 8, j = pp & 255;
    float v = pairf[(size_t)pp*128 + c];
    float s1 = v, s2 = v*v;
    #pragma unroll
    for (int o=32;o>0;o>>=1){ s1 += __shfl_down(s1,o); s2 += __shfl_down(s2,o); }
    __shared__ float r1[2], r2[2], rh[2];
    int lane = c & 63, wid = c >> 6;
    if (lane==0){ r1[wid]=s1; r2[wid]=s2; }
    __syncthreads();
    float m = (r1[0]+r1[1])*(1.f/128.f);
    float q = (r2[0]+r2[1])*(1.f/128.f) - m*m;
    float xn = (v-m)*rsqrtf(q+1e-5f)*toF(w[c]) + toF(b[c]);
    for (int h=0; h<Hn; ++h){
        float p = xn*toF(Wb[c*Hn + h]);
        #pragma unroll
        for (int o=32;o>0;o>>=1) p += __shfl_down(p,o);
        if (lane==0) rh[wid]=p;
        __syncthreads();
        if (c==0){
            float sv = rh[0]+rh[1];
            size_t idx = (mode==0) ? ((size_t)(h*256+j)*256 + i)
                       : (mode==1) ? ((size_t)(i*Hn+h)*256 + j)
                                   : ((size_t)(j*Hn+h)*256 + i);
            outb[idx] = sv;
        }
        __syncthreads();
    }
}

// ---------------- MFMA GEMM (bf16 in, f32 accum): C[M][N] = A[M][K] @ B, B given as B^T [N][K] ----------------
// m97 structure: 128x128 tile, BK=32, 4 waves each 64x64 (4x4 frags of 16x16x32), global_load_lds staging.
// ldbt = row stride of B^T (>= K; sub-blocks of W^T selected by pointer/row offsets).
// ACT: 0 none, 1 sigmoid, 2 relu. MUL: x *= Mul[m (or transposed)]. RES: f32 Res[m+res_off] += x, else C=bf16.
template<int ACT, int MUL, int RES>
__global__ __launch_bounds__(256) void mgemm_k(const bf16* __restrict__ A, const bf16* __restrict__ Bt,
                                               bf16* __restrict__ C, float* __restrict__ Res,
                                               const bf16* __restrict__ Mul,
                                               int M, int N, int K, int ldbt, int res_off, int gtrans){
    __shared__ alignas(16) bf16 As[128*32];
    __shared__ alignas(16) bf16 Bs[128*32];
    const int tid  = threadIdx.x;
    const int m0   = blockIdx.y << 7, n0 = blockIdx.x << 7;
    const int lane = tid & 63, w = tid >> 6;
    const int wr   = (w >> 1) << 6, wc = (w & 1) << 6;   // wave sub-tile origin in the 128x128 tile
    const int fr   = lane & 15, fq = lane >> 4;          // fragment row/col, k-quarter
    // staging: thread t writes 16B at LDS byte t*16 (+4096 for inst 1) == wave base + lane*16 (linear, required)
    const int sr = tid >> 2, sc = (tid & 3) << 3;
    const bf16* ga = A  + (size_t)(m0 + sr)*K    + sc;
    const bf16* gb = Bt + (size_t)(n0 + sr)*ldbt + sc;
    bf16* la = As + tid*8;
    bf16* lb = Bs + tid*8;
    const size_t gaS = (size_t)64*K, gbS = (size_t)64*ldbt;

    f32x4 acc[4][4] = {};
    for (int k0=0; k0<K; k0+=32){
        gload16(ga, la);        gload16(ga + gaS, la + 2048);
        gload16(gb, lb);        gload16(gb + gbS, lb + 2048);
        ga += 32; gb += 32;
        __syncthreads();                                  // drains vmcnt: tiles resident
        i32x4 af[4], bv[4];
        #pragma unroll
        for (int i=0;i<4;i++) af[i] = *(const i32x4*)(As + ((wr + i*16 + fr) << 5) + (fq << 3));
        #pragma unroll
        for (int j=0;j<4;j++) bv[j] = *(const i32x4*)(Bs + ((wc + j*16 + fr) << 5) + (fq << 3));
        #pragma unroll
        for (int i=0;i<4;i++)
            #pragma unroll
            for (int j=0;j<4;j++)
                asm("v_mfma_f32_16x16x32_bf16 %0, %1, %2, %0"
                    : "+v"(acc[i][j]) : "v"(af[i]), "v"(bv[j]));
        __syncthreads();                                  // all reads done before next-tile staging
    }
    // epilogue: D lane layout (verified m89/m91): col = lane&15, row = (lane>>4)*4 + reg
    #pragma unroll
    for (int i=0;i<4;i++){
        const int mB = m0 + wr + i*16 + (fq << 2);
        #pragma unroll
        for (int j=0;j<4;j++){
            const int n = n0 + wc + j*16 + fr;
            #pragma unroll
            for (int r=0;r<4;r++){
                int m = mB + r;
                float x = acc[i][j][r];
                if (ACT==1) x = 1.f/(1.f + __expf(-x));
                else if (ACT==2) x = fmaxf(x, 0.f);
                if (MUL){
                    int mr = gtrans ? (((m & 255) << 8) | (m >> 8)) : m;
                    x *= toF(Mul[(size_t)mr*N + n]);
                }
                if (RES) Res[(size_t)(m + res_off)*N + n] += x;
                else     C[(size_t)m*N + n] = toB(x);
            }
        }
    }
}

// ---------------- legacy VALU GEMM (kept only for N=32 outer projections) ----------------
template<int ACT, int MUL, int RES>
__global__ __launch_bounds__(256) void gemm_k(const bf16* __restrict__ A, const bf16* __restrict__ Bw,
                                              bf16* __restrict__ C, float* __restrict__ Res,
                                              const bf16* __restrict__ Mul,
                                              int M, int N, int K, int ldb, int res_off, int gtrans){
    __shared__ float As[64][33];
    __shared__ float Bs[32][65];
    int tid = threadIdx.x;
    int m0 = blockIdx.y*64, n0 = blockIdx.x*64;
    int tx = tid & 15, ty = tid >> 4;
    float acc[4][4] = {};
    for (int k0=0; k0<K; k0+=32){
        for (int i=tid; i<64*32; i+=256){
            int r = i>>5, cc = i&31;
            As[r][cc] = toF(A[(size_t)(m0+r)*K + k0 + cc]);
        }
        for (int i=tid; i<32*64; i+=256){
            int r = i>>6, cc = i&63; int col = n0+cc;
            Bs[r][cc] = (col < N) ? toF(Bw[(size_t)(k0+r)*ldb + col]) : 0.f;
        }
        __syncthreads();
        #pragma unroll 8
        for (int k=0;k<32;k++){
            float a4[4], b4[4];
            #pragma unroll
            for (int i=0;i<4;i++) a4[i] = As[ty*4+i][k];
            #pragma unroll
            for (int j=0;j<4;j++) b4[j] = Bs[k][tx*4+j];
            #pragma unroll
            for (int i=0;i<4;i++)
                #pragma unroll
                for (int j=0;j<4;j++) acc[i][j] += a4[i]*b4[j];
        }
        __syncthreads();
    }
    #pragma unroll
    for (int i=0;i<4;i++){
        int m = m0 + ty*4 + i;
        #pragma unroll
        for (int j=0;j<4;j++){
            int n = n0 + tx*4 + j;
            if (n >= N) continue;
            float x = acc[i][j];
            if (ACT==1) x = 1.f/(1.f + __expf(-x));
            else if (ACT==2) x = fmaxf(x, 0.f);
            if (MUL){
                int mr = gtrans ? (((m & 255) << 8) | (m >> 8)) : m;
                x *= toF(Mul[(size_t)mr*N + n]);
            }
            if (RES) Res[(size_t)(m + res_off)*N + n] += x;
            else     C[(size_t)m*N + n] = toB(x);
        }
    }
}

// ---------------- attention v3: lane-per-query, register flash softmax ----------------
template<int BIAS, int L, int NW>
__global__ __launch_bounds__(NW*64) void attn3_k(bf16* __restrict__ QO,
                                                 const bf16* __restrict__ Kp, const bf16* __restrict__ Vp,
                                                 const float* __restrict__ bias,
                                                 int H, int sO, int sL){
    __shared__ float Kt[L*32];
    __shared__ float Vt[L*32];
    const int o = blockIdx.y, h = blockIdx.x, tid = threadIdx.x;
    const int GN = H*32;
    for (int idx=tid; idx<L*16; idx+=NW*64){      // 2 bf16 per iteration
        int l = idx >> 4, c2 = (idx & 15)*2;
        size_t p = (size_t)(o*sO + l*sL)*GN + h*32 + c2;
        uint32_t kk = *(const uint32_t*)(Kp + p);
        uint32_t vv = *(const uint32_t*)(Vp + p);
        Kt[l*32 + c2]   = __uint_as_float(kk << 16);
        Kt[l*32 + c2+1] = __uint_as_float(kk & 0xFFFF0000u);
        Vt[l*32 + c2]   = __uint_as_float(vv << 16);
        Vt[l*32 + c2+1] = __uint_as_float(vv & 0xFFFF0000u);
    }
    __syncthreads();
    const int q = tid;
    size_t pq = (size_t)(o*sO + q*sL)*GN + h*32;
    float qv[32];
    {   const uint4* qp = (const uint4*)(QO + pq);   // 64B aligned
        #pragma unroll
        for (int i=0;i<4;i++){
            uint4 r = qp[i];
            uint32_t u0=r.x,u1=r.y,u2=r.z,u3=r.w;
            qv[i*8+0]=__uint_as_float(u0<<16); qv[i*8+1]=__uint_as_float(u0&0xFFFF0000u);
            qv[i*8+2]=__uint_as_float(u1<<16); qv[i*8+3]=__uint_as_float(u1&0xFFFF0000u);
            qv[i*8+4]=__uint_as_float(u2<<16); qv[i*8+5]=__uint_as_float(u2&0xFFFF0000u);
            qv[i*8+6]=__uint_as_float(u3<<16); qv[i*8+7]=__uint_as_float(u3&0xFFFF0000u);
        }
    }
    float Os[32], Ob[32];
    #pragma unroll
    for (int c=0;c<32;c++){ Os[c]=0.f; Ob[c]=0.f; }
    float lsum = 0.f;
    const float* bp = (BIAS==1) ? (bias + (size_t)h*65536 + q)
                    : (BIAS==2) ? (bias + ((size_t)(o*H+h))*256) : (const float*)nullptr;
    for (int k=0;k<L;k++){
        float s = 0.f;
        #pragma unroll
        for (int c=0;c<32;c++) s += qv[c]*Kt[k*32+c];
        float e = __expf(s * 0.17677669529663687f);   // 1/sqrt(32) folded into exp arg
        lsum += e;
        #pragma unroll
        for (int c=0;c<32;c++) Os[c] += e*Vt[k*32+c];
        if (BIAS){
            float bv = (BIAS==1) ? bp[(size_t)k*256] : bp[k];
            #pragma unroll
            for (int c=0;c<32;c++) Ob[c] += bv*Vt[k*32+c];
        }
    }
    float inv = 1.f/lsum;
    #pragma unroll
    for (int c=0;c<32;c++)
        QO[pq + c] = toB(Os[c]*inv + (BIAS ? Ob[c] : 0.f));
}

// ---------------- elementwise: a *= sigmoid(g) ----------------
__global__ void mulsig_k(bf16* __restrict__ a, const bf16* __restrict__ g, int n){
    int i = blockIdx.x*256 + threadIdx.x;
    if (i < n){
        float sg = 1.f/(1.f + __expf(-toF(g[i])));
        a[i] = toB(toF(a[i]) * sg);
    }
}

// ---------------- triangle multiplication einsum ----------------
__global__ void trimul_k(const bf16* __restrict__ a, const bf16* __restrict__ b, bf16* __restrict__ p, int incoming){
    int t = blockIdx.x, s = blockIdx.y, k = threadIdx.x;   // 128 threads
    float acc = 0.f;
    if (!incoming){
        const bf16* pa = a + (size_t)(s*256)*128 + k;
        const bf16* pb = b + (size_t)(t*256)*128 + k;
        for (int r=0;r<256;r++) acc += toF(pa[(size_t)r*128]) * toF(pb[(size_t)r*128]);
    } else {
        const bf16* pa = a + (size_t)s*128 + k;
        const bf16* pb = b + (size_t)t*128 + k;
        for (int r=0;r<256;r++) acc += toF(pa[(size_t)r*32768]) * toF(pb[(size_t)r*32768]);
    }
    p[((size_t)s*256 + t)*128 + k] = toB(acc);
}

// ---------------- outer product einsum, chunked over r (32 r's per chunk) ----------------
__global__ __launch_bounds__(256) void outer_k(const bf16* __restrict__ ap, const bf16* __restrict__ bp,
                                               bf16* __restrict__ outc, int r0){
    int t = blockIdx.x, rl = blockIdx.y, r = r0 + rl;
    __shared__ float As[128*32], Bs[128*32];
    for (int idx=threadIdx.x; idx<128*32; idx+=256){
        int s = idx>>5, c = idx&31;
        As[idx] = toF(ap[((size_t)s*256 + r)*32 + c]);
        Bs[idx] = toF(bp[((size_t)s*256 + t)*32 + c]);
    }
    __syncthreads();
    int ce0 = threadIdx.x*4;
    int c = ce0 >> 5, e0 = ce0 & 31;
    float acc[4] = {0.f,0.f,0.f,0.f};
    for (int s=0;s<128;s++){
        float av = As[s*32 + c];
        #pragma unroll
        for (int j=0;j<4;j++) acc[j] += av*Bs[s*32 + e0 + j];
    }
    size_t row = (size_t)rl*256 + t;
    #pragma unroll
    for (int j=0;j<4;j++) outc[row*1024 + ce0 + j] = toB(acc[j]);
}

// ================= host =================
// GEMM-B weight shapes (K,N) for transpose staging; false => plain staging
static bool tshape(int i, int& K, int& N){
    switch(i){
        case 6: case 8: case 12: case 14: K=256; N=256;  return true;   // msa gate/out
        case 7: case 13:                  K=256; N=768;  return true;   // msa qkv
        case 17:                          K=256; N=1024; return true;   // mt_p1
        case 18:                          K=1024;N=256;  return true;   // mt_p2
        case 23:                          K=1024;N=128;  return true;   // outer_out
        case 47: case 53:                 K=128; N=384;  return true;   // tri qkv
        case 58:                          K=128; N=512;  return true;   // pt_p1
        case 59:                          K=512; N=128;  return true;   // pt_p2
        default:
            if ((i>=28&&i<=33)||(i>=38&&i<=43)||i==46||i==48||i==52||i==54){ K=128; N=128; return true; }
            return false;
    }
}

extern "C" void kernel_launch(void* const* d_in, const int* in_sizes, int n_in,
                              void* d_out, int out_size, void* d_ws, size_t ws_size,
                              hipStream_t stream){
    (void)n_in; (void)out_size; (void)ws_size;
    const int MSA_N  = 128*256*256;   // 8388608
    const int PAIR_N = 256*256*128;   // 8388608
    const uint32_t* probe = (const uint32_t*)d_in[2];   // row_norm_m_w = ones

    // ---- workspace layout: 70 MB ----
    char*  w     = (char*)d_ws;
    bf16*  wsts  = (bf16*)(w);                 // [0, 4MB) staged bf16 weights (GEMM ones transposed)
    float* biasF = (float*)(w + 4194304);      // [4MB, 6MB)
    bf16*  lnb   = (bf16*)(w + 6291456);       // [6MB, 22MB)
    bf16*  bufA  = (bf16*)(w + 23068672);      // [22MB, 38MB)
    bf16*  bufB  = (bf16*)(w + 39845888);      // [38MB, 54MB)
    bf16*  bufC  = (bf16*)(w + 56623104);      // [54MB, 70MB)

    float* msaF  = (float*)d_out;              // f32 msa accumulator == output 0
    float* pairF = msaF + MSA_N;               // f32 pair accumulator == output 1

    // ---- stage all weights (inputs 2..59) to bf16; GEMM weights transposed ----
    size_t woff[64]; { size_t acc = 0;
        for (int i=2;i<60;i++){ woff[i] = acc; acc += ((size_t)in_sizes[i] + 63) & ~(size_t)63; } }
    #define W(i) (wsts + woff[i])
    for (int i=2;i<60;i++){
        int tk, tn;
        if (tshape(i, tk, tn))
            cvt_wT_k<<<(in_sizes[i]+255)/256,256,0,stream>>>(d_in[i], W(i), tk, tn, probe);
        else
            cvt_w_k<<<(in_sizes[i]+255)/256,256,0,stream>>>(d_in[i], W(i), in_sizes[i], probe);
    }

    in2f_k<<<32768,256,0,stream>>>(d_in[0], msaF,  MSA_N,  probe);
    in2f_k<<<32768,256,0,stream>>>(d_in[1], pairF, PAIR_N, probe);

    #define GEMM_GRID(M,N) dim3(((N)+63)/64, (M)/64)
    #define MG(M,N)        dim3((N)/128, (M)/128)

    // ================= Row attention (bias = LN(pair)@row_bias, post-softmax) =================
    ln_k<float><<<32768,256,0,stream>>>(msaF, W(2), W(3), lnb, 256);
    ln_bias_k<<<65536,128,0,stream>>>(pairF, W(4), W(5), W(9), biasF, 8, 0);
    mgemm_k<0,0,0><<<MG(32768,256),256,0,stream>>>(lnb, W(7),        bufA, nullptr, nullptr, 32768,256,256, 256, 0,0); // Q
    mgemm_k<0,0,0><<<MG(32768,256),256,0,stream>>>(lnb, W(7)+65536,  bufB, nullptr, nullptr, 32768,256,256, 256, 0,0); // K
    mgemm_k<0,0,0><<<MG(32768,256),256,0,stream>>>(lnb, W(7)+131072, bufC, nullptr, nullptr, 32768,256,256, 256, 0,0); // V
    attn3_k<1,256,4><<<dim3(8,128),256,0,stream>>>(bufA, bufB, bufC, biasF, 8, 256, 1);
    mgemm_k<0,0,0><<<MG(32768,256),256,0,stream>>>(lnb, W(6), bufB, nullptr, nullptr, 32768,256,256, 256, 0,0);        // gate raw
    mulsig_k<<<32768,256,0,stream>>>(bufA, bufB, MSA_N);
    mgemm_k<0,0,1><<<MG(32768,256),256,0,stream>>>(bufA, W(8), nullptr, msaF, nullptr, 32768,256,256, 256, 0,0);

    // ================= Column attention (attend over s, L=128, no bias) =================
    ln_k<float><<<32768,256,0,stream>>>(msaF, W(10), W(11), lnb, 256);
    mgemm_k<0,0,0><<<MG(32768,256),256,0,stream>>>(lnb, W(13),        bufA, nullptr, nullptr, 32768,256,256, 256, 0,0);
    mgemm_k<0,0,0><<<MG(32768,256),256,0,stream>>>(lnb, W(13)+65536,  bufB, nullptr, nullptr, 32768,256,256, 256, 0,0);
    mgemm_k<0,0,0><<<MG(32768,256),256,0,stream>>>(lnb, W(13)+131072, bufC, nullptr, nullptr, 32768,256,256, 256, 0,0);
    attn3_k<0,128,2><<<dim3(8,256),128,0,stream>>>(bufA, bufB, bufC, nullptr, 8, 1, 256);
    mgemm_k<0,0,0><<<MG(32768,256),256,0,stream>>>(lnb, W(12), bufB, nullptr, nullptr, 32768,256,256, 256, 0,0);
    mulsig_k<<<32768,256,0,stream>>>(bufA, bufB, MSA_N);
    mgemm_k<0,0,1><<<MG(32768,256),256,0,stream>>>(bufA, W(14), nullptr, msaF, nullptr, 32768,256,256, 256, 0,0);

    // ================= MSA transition (FF chunked 4 x 256) =================
    ln_k<float><<<32768,256,0,stream>>>(msaF, W(15), W(16), lnb, 256);
    for (int ch=0; ch<4; ++ch){
        mgemm_k<2,0,0><<<MG(32768,256),256,0,stream>>>(lnb, W(17)+ch*65536, bufA, nullptr, nullptr, 32768,256,256, 256, 0,0);
        mgemm_k<0,0,1><<<MG(32768,256),256,0,stream>>>(bufA, W(18)+ch*256, nullptr, msaF, nullptr, 32768,256,256, 1024, 0,0);
    }

    // ================= Outer product mean (chunked 8 x 32 r's; chunks reuse lnb) =================
    ln_k<float><<<32768,256,0,stream>>>(msaF, W(19), W(20), lnb, 256);
    gemm_k<0,0,0><<<GEMM_GRID(32768,32),256,0,stream>>>(lnb, W(21), bufA, nullptr, nullptr, 32768,32,256, 32, 0,0);
    gemm_k<0,0,0><<<GEMM_GRID(32768,32),256,0,stream>>>(lnb, W(22), bufB, nullptr, nullptr, 32768,32,256, 32, 0,0);
    for (int ch=0; ch<8; ++ch){   // lnb dead; reuse as 8192x1024 chunk buffer
        outer_k<<<dim3(256,32),256,0,stream>>>(bufA, bufB, lnb, ch*32);
        mgemm_k<0,0,1><<<MG(8192,128),256,0,stream>>>(lnb, W(23), nullptr, pairF, nullptr, 8192,128,1024, 1024, ch*8192,0);
    }

    // ================= Triangle mult outgoing / incoming =================
    for (int tm=0; tm<2; ++tm){
        int o = tm ? 34 : 24;   // tmi_* : tmo_*
        int inc = tm;
        ln_k<float><<<65536,128,0,stream>>>(pairF, W(o+0), W(o+1), lnb, 128);
        mgemm_k<1,0,0><<<MG(65536,128),256,0,stream>>>(lnb, W(o+4), bufA, nullptr, nullptr, 65536,128,128, 128, 0,0); // sig(xn@p1)
        mgemm_k<0,1,0><<<MG(65536,128),256,0,stream>>>(lnb, W(o+5), bufA, nullptr, bufA,   65536,128,128, 128, 0,0); // a
        mgemm_k<1,0,0><<<MG(65536,128),256,0,stream>>>(lnb, W(o+6), bufB, nullptr, nullptr, 65536,128,128, 128, 0,0); // sig(xn@p3)
        mgemm_k<0,1,0><<<MG(65536,128),256,0,stream>>>(lnb, W(o+7), bufB, nullptr, bufB,   65536,128,128, 128, 0,0); // b
        trimul_k<<<dim3(256,256),128,0,stream>>>(bufA, bufB, bufC, inc);      // p -> bufC
        ln_k<bf16><<<65536,128,0,stream>>>(bufC, W(o+2), W(o+3), bufC, 128);  // LN(p) in place
        mgemm_k<1,0,0><<<MG(65536,128),256,0,stream>>>(lnb, W(o+9), bufA, nullptr, nullptr, 65536,128,128, 128, 0,0); // g (lnb intact)
        mgemm_k<0,1,1><<<MG(65536,128),256,0,stream>>>(bufC, W(o+8), nullptr, pairF, bufA, 65536,128,128, 128, 0, inc);
    }

    // ================= Triangle attention starting (tas) =================
    ln_k<float><<<65536,128,0,stream>>>(pairF, W(44), W(45), lnb, 128);
    ln_bias_k<<<65536,128,0,stream>>>(pairF, W(44), W(45), W(49), biasF, 4, 1);
    mgemm_k<0,0,0><<<MG(65536,128),256,0,stream>>>(lnb, W(47),       bufA, nullptr, nullptr, 65536,128,128, 128, 0,0);
    mgemm_k<0,0,0><<<MG(65536,128),256,0,stream>>>(lnb, W(47)+16384, bufB, nullptr, nullptr, 65536,128,128, 128, 0,0);
    mgemm_k<0,0,0><<<MG(65536,128),256,0,stream>>>(lnb, W(47)+32768, bufC, nullptr, nullptr, 65536,128,128, 128, 0,0);
    attn3_k<2,256,4><<<dim3(4,256),256,0,stream>>>(bufA, bufB, bufC, biasF, 4, 256, 1);
    mgemm_k<0,0,0><<<MG(65536,128),256,0,stream>>>(lnb, W(46), bufB, nullptr, nullptr, 65536,128,128, 128, 0,0);
    mulsig_k<<<32768,256,0,stream>>>(bufA, bufB, PAIR_N);
    mgemm_k<0,0,1><<<MG(65536,128),256,0,stream>>>(bufA, W(48), nullptr, pairF, nullptr, 65536,128,128, 128, 0,0);

    // ================= Triangle attention ending (tae) =================
    ln_k<float><<<65536,128,0,stream>>>(pairF, W(50), W(51), lnb, 128);
    ln_bias_k<<<65536,128,0,stream>>>(pairF, W(50), W(51), W(55), biasF, 4, 2);
    mgemm_k<0,0,0><<<MG(65536,128),256,0,stream>>>(lnb, W(53),       bufA, nullptr, nullptr, 65536,128,128, 128, 0,0);
    mgemm_k<0,0,0><<<MG(65536,128),256,0,stream>>>(lnb, W(53)+16384, bufB, nullptr, nullptr, 65536,128,128, 128, 0,0);
    mgemm_k<0,0,0><<<MG(65536,128),256,0,stream>>>(lnb, W(53)+32768, bufC, nullptr, nullptr, 65536,128,128, 128, 0,0);
    attn3_k<2,256,4><<<dim3(4,256),256,0,stream>>>(bufA, bufB, bufC, biasF, 4, 1, 256);
    mgemm_k<0,0,0><<<MG(65536,128),256,0,stream>>>(lnb, W(52), bufB, nullptr, nullptr, 65536,128,128, 128, 0,0);
    mulsig_k<<<32768,256,0,stream>>>(bufA, bufB, PAIR_N);
    mgemm_k<0,0,1><<<MG(65536,128),256,0,stream>>>(bufA, W(54), nullptr, pairF, nullptr, 65536,128,128, 128, 0,0);

    // ================= Pair transition (FF chunked 4 x 128) =================
    ln_k<float><<<65536,128,0,stream>>>(pairF, W(56), W(57), lnb, 128);
    for (int ch=0; ch<4; ++ch){
        mgemm_k<2,0,0><<<MG(65536,128),256,0,stream>>>(lnb, W(58)+ch*16384, bufA, nullptr, nullptr, 65536,128,128, 128, 0,0);
        mgemm_k<0,0,1><<<MG(65536,128),256,0,stream>>>(bufA, W(59)+ch*128, nullptr, pairF, nullptr, 65536,128,128, 512, 0,0);
    }
    // outputs are msaF/pairF in d_out (f32) — done.
}

// Round 2
// 3170.659 us; speedup vs baseline: 1.2562x; 1.2562x over previous
//
#include <hip/hip_runtime.h>
#include <hip/hip_bf16.h>
#include <stdint.h>

typedef __hip_bfloat16 bf16;
typedef __attribute__((ext_vector_type(4))) int   i32x4;
typedef __attribute__((ext_vector_type(4))) float f32x4;

// Shapes (N=1): S=128, R=256, CM=256, CZ=128, C=32, MSA_H=8, PAIR_H=4, CTM=128, FF=4
// msa rows: s*256+r (32768 x 256); pair rows: i*256+j (65536 x 128)
// I/O dtype: FLOAT32. Accumulators f32 live directly in d_out (they ARE the outputs).
// Workspace (70 MB): weights 4MB | biasF 2MB | lnb 16MB | bufA 16MB | bufB 16MB | bufC 16MB.
// GEMM weights are staged TRANSPOSED (W^T [N][K]) so MFMA B-fragments read k-contiguous bf16x8.

__device__ __forceinline__ float toF(float x){ return x; }
__device__ __forceinline__ float toF(bf16 x){ return __bfloat162float(x); }
__device__ __forceinline__ bf16  toB(float x){ return __float2bfloat16(x); }

__device__ __forceinline__ void gload16(const bf16* g, bf16* l){
    __builtin_amdgcn_global_load_lds((const __attribute__((address_space(1))) void*)g,
                                     (__attribute__((address_space(3))) void*)l, 16, 0, 0);
}

// ---------------- input staging (dtype probe: bf16 ones -> 0x3F803F80, f32 one -> 0x3F800000) ----------------
__global__ void cvt_w_k(const void* __restrict__ in, bf16* __restrict__ out, int n,
                        const uint32_t* __restrict__ probe){
    bool isbf = (probe[0] == 0x3F803F80u);
    int i = blockIdx.x*256 + threadIdx.x;
    if (i < n) out[i] = isbf ? ((const bf16*)in)[i] : toB(((const float*)in)[i]);
}
// transpose-staging for GEMM B operands: in [K][N] row-major -> out [N][K] row-major
__global__ void cvt_wT_k(const void* __restrict__ in, bf16* __restrict__ out, int K, int N,
                         const uint32_t* __restrict__ probe){
    bool isbf = (probe[0] == 0x3F803F80u);
    int i = blockIdx.x*256 + threadIdx.x;
    if (i < K*N){
        float v = isbf ? toF(((const bf16*)in)[i]) : ((const float*)in)[i];
        int k = i / N, n = i - k*N;
        out[(size_t)n*K + k] = toB(v);
    }
}
__global__ void in2f_k(const void* __restrict__ in, float* __restrict__ out, int n,
                       const uint32_t* __restrict__ probe){
    bool isbf = (probe[0] == 0x3F803F80u);
    int i = blockIdx.x*256 + threadIdx.x;
    if (i < n) out[i] = isbf ? toF(((const bf16*)in)[i]) : ((const float*)in)[i];
}

// ---------------- LayerNorm: one block per row, blockDim = D (128 or 256); in-place safe ----------------
template<typename T>
__global__ void ln_k(const T* __restrict__ x, const bf16* __restrict__ w, const bf16* __restrict__ b,
                     bf16* __restrict__ out, int D){
    int row = blockIdx.x, c = threadIdx.x;
    float v = toF(x[(size_t)row*D + c]);
    float s1 = v, s2 = v*v;
    #pragma unroll
    for (int o=32;o>0;o>>=1){ s1 += __shfl_down(s1,o); s2 += __shfl_down(s2,o); }
    __shared__ float r1[4], r2[4];
    int lane = c & 63, wid = c >> 6;
    if (lane==0){ r1[wid]=s1; r2[wid]=s2; }
    __syncthreads();
    int nw = blockDim.x >> 6;
    float m=0.f, q=0.f;
    for (int i=0;i<nw;i++){ m+=r1[i]; q+=r2[i]; }
    m /= (float)D; q = q/(float)D - m*m;
    float inv = rsqrtf(q + 1e-5f);
    out[(size_t)row*D + c] = toB((v-m)*inv*toF(w[c]) + toF(b[c]));
}

// ---------------- fused LN + attention-bias projection (reads f32 pair acc) ----------------
// mode 0 (row attn, Hn=8): out[(h*256+j)*256+i]  ([h][k][q] layout -> lane-coalesced reads)
// mode 1 (tas, Hn=4):      out[(i*Hn+h)*256+j]
// mode 2 (tae, Hn=4):      out[(j*Hn+h)*256+i].  Value = dot(LN(pair[i,j]), Wb[:,h]).
__global__ void ln_bias_k(const float* __restrict__ pairf, const bf16* __restrict__ w, const bf16* __restrict__ b,
                          const bf16* __restrict__ Wb, float* __restrict__ outb, int Hn, int mode){
    int pp = blockIdx.x, c = threadIdx.x;           // 128 threads
    int i = pp >> 8, j = pp & 255;
    float v = pairf[(size_t)pp*128 + c];
    float s1 = v, s2 = v*v;
    #pragma unroll
    for (int o=32;o>0;o>>=1){ s1 += __shfl_down(s1,o); s2 += __shfl_down(s2,o); }
    __shared__ float r1[2], r2[2], rh[2];
    int lane = c & 63, wid = c >> 6;
    if (lane==0){ r1[wid]=s1; r2[wid]=s2; }
    __syncthreads();
    float m = (r1[0]+r1[1])*(1.f/128.f);
    float q = (r2[0]+r2[1])*(1.f/128.f) - m*m;
    float xn = (v-m)*rsqrtf(q+1e-5f)*toF(w[c]) + toF(b[c]);
    for (int h=0; h<Hn; ++h){
        float p = xn*toF(Wb[c*Hn + h]);
        #pragma unroll
        for (int o=32;o>0;o>>=1) p += __shfl_down(p,o);
        if (lane==0) rh[wid]=p;
        __syncthreads();
        if (c==0){
            float sv = rh[0]+rh[1];
            size_t idx = (mode==0) ? ((size_t)(h*256+j)*256 + i)
                       : (mode==1) ? ((size_t)(i*Hn+h)*256 + j)
                                   : ((size_t)(j*Hn+h)*256 + i);
            outb[idx] = sv;
        }
        __syncthreads();
    }
}

// ---------------- MFMA GEMM (bf16 in, f32 accum): C[M][N] = A[M][K] @ B, B given as B^T [N][K] ----------------
// m97 structure: 128x128 tile, BK=32, 4 waves each 64x64 (4x4 frags of 16x16x32), global_load_lds staging.
// ACT: 0 none, 1 sigmoid, 2 relu. MUL: x *= Mul[m (or transposed)]. RES: f32 Res[m+res_off] += x, else C=bf16.
template<int ACT, int MUL, int RES>
__global__ __launch_bounds__(256) void mgemm_k(const bf16* __restrict__ A, const bf16* __restrict__ Bt,
                                               bf16* __restrict__ C, float* __restrict__ Res,
                                               const bf16* __restrict__ Mul,
                                               int M, int N, int K, int ldbt, int res_off, int gtrans){
    __shared__ alignas(16) bf16 As[128*32];
    __shared__ alignas(16) bf16 Bs[128*32];
    const int tid  = threadIdx.x;
    const int m0   = blockIdx.y << 7, n0 = blockIdx.x << 7;
    const int lane = tid & 63, w = tid >> 6;
    const int wr   = (w >> 1) << 6, wc = (w & 1) << 6;   // wave sub-tile origin in the 128x128 tile
    const int fr   = lane & 15, fq = lane >> 4;          // fragment row/col, k-quarter
    const int sr = tid >> 2, sc = (tid & 3) << 3;
    const bf16* ga = A  + (size_t)(m0 + sr)*K    + sc;
    const bf16* gb = Bt + (size_t)(n0 + sr)*ldbt + sc;
    bf16* la = As + tid*8;
    bf16* lb = Bs + tid*8;
    const size_t gaS = (size_t)64*K, gbS = (size_t)64*ldbt;

    f32x4 acc[4][4] = {};
    for (int k0=0; k0<K; k0+=32){
        gload16(ga, la);        gload16(ga + gaS, la + 2048);
        gload16(gb, lb);        gload16(gb + gbS, lb + 2048);
        ga += 32; gb += 32;
        __syncthreads();                                  // drains vmcnt: tiles resident
        i32x4 af[4], bv[4];
        #pragma unroll
        for (int i=0;i<4;i++) af[i] = *(const i32x4*)(As + ((wr + i*16 + fr) << 5) + (fq << 3));
        #pragma unroll
        for (int j=0;j<4;j++) bv[j] = *(const i32x4*)(Bs + ((wc + j*16 + fr) << 5) + (fq << 3));
        #pragma unroll
        for (int i=0;i<4;i++)
            #pragma unroll
            for (int j=0;j<4;j++)
                asm("v_mfma_f32_16x16x32_bf16 %0, %1, %2, %0"
                    : "+v"(acc[i][j]) : "v"(af[i]), "v"(bv[j]));
        __syncthreads();                                  // all reads done before next-tile staging
    }
    // epilogue: D lane layout (verified m89/m91): col = lane&15, row = (lane>>4)*4 + reg
    #pragma unroll
    for (int i=0;i<4;i++){
        const int mB = m0 + wr + i*16 + (fq << 2);
        #pragma unroll
        for (int j=0;j<4;j++){
            const int n = n0 + wc + j*16 + fr;
            #pragma unroll
            for (int r=0;r<4;r++){
                int m = mB + r;
                float x = acc[i][j][r];
                if (ACT==1) x = 1.f/(1.f + __expf(-x));
                else if (ACT==2) x = fmaxf(x, 0.f);
                if (MUL){
                    int mr = gtrans ? (((m & 255) << 8) | (m >> 8)) : m;
                    x *= toF(Mul[(size_t)mr*N + n]);
                }
                if (RES) Res[(size_t)(m + res_off)*N + n] += x;
                else     C[(size_t)m*N + n] = toB(x);
            }
        }
    }
}

// ---------------- batched MFMA GEMM for triangle mult: per-k C_k = A_k @ B_k^T (256x256x256) ----------------
// aT/bT: [128][256][256] k-major slices, reduction dim contiguous. pT out in same k-major layout.
__global__ __launch_bounds__(256) void btrimul_k(const bf16* __restrict__ aT, const bf16* __restrict__ bT,
                                                 bf16* __restrict__ pT){
    __shared__ alignas(16) bf16 As[128*32];
    __shared__ alignas(16) bf16 Bs[128*32];
    const int tid  = threadIdx.x;
    const int m0   = blockIdx.y << 7, n0 = blockIdx.x << 7;
    const size_t zb = (size_t)blockIdx.z << 16;           // k*65536
    const int lane = tid & 63, w = tid >> 6;
    const int wr   = (w >> 1) << 6, wc = (w & 1) << 6;
    const int fr   = lane & 15, fq = lane >> 4;
    const int sr = tid >> 2, sc = (tid & 3) << 3;
    const bf16* ga = aT + zb + (size_t)(m0 + sr)*256 + sc;
    const bf16* gb = bT + zb + (size_t)(n0 + sr)*256 + sc;
    bf16* la = As + tid*8;
    bf16* lb = Bs + tid*8;
    const size_t gS = (size_t)64*256;

    f32x4 acc[4][4] = {};
    for (int k0=0; k0<256; k0+=32){
        gload16(ga, la);        gload16(ga + gS, la + 2048);
        gload16(gb, lb);        gload16(gb + gS, lb + 2048);
        ga += 32; gb += 32;
        __syncthreads();
        i32x4 af[4], bv[4];
        #pragma unroll
        for (int i=0;i<4;i++) af[i] = *(const i32x4*)(As + ((wr + i*16 + fr) << 5) + (fq << 3));
        #pragma unroll
        for (int j=0;j<4;j++) bv[j] = *(const i32x4*)(Bs + ((wc + j*16 + fr) << 5) + (fq << 3));
        #pragma unroll
        for (int i=0;i<4;i++)
            #pragma unroll
            for (int j=0;j<4;j++)
                asm("v_mfma_f32_16x16x32_bf16 %0, %1, %2, %0"
                    : "+v"(acc[i][j]) : "v"(af[i]), "v"(bv[j]));
        __syncthreads();
    }
    #pragma unroll
    for (int i=0;i<4;i++){
        const int mB = m0 + wr + i*16 + (fq << 2);
        #pragma unroll
        for (int j=0;j<4;j++){
            const int n = n0 + wc + j*16 + fr;
            #pragma unroll
            for (int r=0;r<4;r++)
                pT[zb + (size_t)(mB + r)*256 + n] = toB(acc[i][j][r]);
        }
    }
}

// ---------------- row/channel transposes for triangle mult ----------------
// rc2k_k: in [65536][128] (row pp = i*256+j, k contiguous) -> out [128][256][256] k-major.
// swap=0: out[k*65536 + i*256 + j]   (tile: 128 consecutive pp, i fixed)
// swap=1: out[k*65536 + j*256 + i]   (tile: j fixed, i in [I0,I0+128))
// Both modes: reads and writes are 256B-contiguous runs (coalesced).
__global__ __launch_bounds__(256) void rc2k_k(const bf16* __restrict__ in, bf16* __restrict__ out, int swap){
    __shared__ uint16_t T[128][137];
    const int tt = blockIdx.x, tid = threadIdx.x;
    size_t base_pp, out_off; int ppstride;
    if (!swap){ base_pp = (size_t)tt*128;                  ppstride = 1;   out_off = (size_t)tt*128; }
    else      { int J = tt>>1, I0 = (tt&1)*128;
                base_pp = (size_t)I0*256 + J;              ppstride = 256; out_off = (size_t)J*256 + I0; }
    for (int it=0; it<8; ++it){
        int idx = tid + it*256;                 // [0,2048): 16B chunks
        int r = idx >> 4, c8 = (idx & 15) << 3;
        uint4 v = *(const uint4*)(in + (base_pp + (size_t)r*ppstride)*128 + c8);
        uint16_t tmp[8]; *(uint4*)tmp = v;
        #pragma unroll
        for (int t=0;t<8;t++) T[r][c8+t] = tmp[t];
    }
    __syncthreads();
    for (int it=0; it<8; ++it){
        int idx = tid + it*256;
        int k = idx >> 4, r8 = (idx & 15) << 3;
        uint16_t tmp[8];
        #pragma unroll
        for (int t=0;t<8;t++) tmp[t] = T[r8+t][k];
        *(uint4*)(out + (size_t)k*65536 + out_off + r8) = *(uint4*)tmp;
    }
}
// k2rc_k: in [128][65536] k-major -> out [65536][128] (k contiguous). Mirror of rc2k swap=0.
__global__ __launch_bounds__(256) void k2rc_k(const bf16* __restrict__ in, bf16* __restrict__ out){
    __shared__ uint16_t T[128][137];
    const int tt = blockIdx.x, tid = threadIdx.x;
    const size_t a0 = (size_t)tt*128;
    for (int it=0; it<8; ++it){
        int idx = tid + it*256;
        int k = idx >> 4, r8 = (idx & 15) << 3;
        uint4 v = *(const uint4*)(in + (size_t)k*65536 + a0 + r8);
        uint16_t tmp[8]; *(uint4*)tmp = v;
        #pragma unroll
        for (int t=0;t<8;t++) T[r8+t][k] = tmp[t];
    }
    __syncthreads();
    for (int it=0; it<8; ++it){
        int idx = tid + it*256;
        int r = idx >> 4, c8 = (idx & 15) << 3;
        uint16_t tmp[8];
        #pragma unroll
        for (int t=0;t<8;t++) tmp[t] = T[r][c8+t];
        *(uint4*)(out + (a0 + r)*128 + c8) = *(uint4*)tmp;
    }
}

// ---------------- legacy VALU GEMM (kept only for N=32 outer projections) ----------------
template<int ACT, int MUL, int RES>
__global__ __launch_bounds__(256) void gemm_k(const bf16* __restrict__ A, const bf16* __restrict__ Bw,
                                              bf16* __restrict__ C, float* __restrict__ Res,
                                              const bf16* __restrict__ Mul,
                                              int M, int N, int K, int ldb, int res_off, int gtrans){
    __shared__ float As[64][33];
    __shared__ float Bs[32][65];
    int tid = threadIdx.x;
    int m0 = blockIdx.y*64, n0 = blockIdx.x*64;
    int tx = tid & 15, ty = tid >> 4;
    float acc[4][4] = {};
    for (int k0=0; k0<K; k0+=32){
        for (int i=tid; i<64*32; i+=256){
            int r = i>>5, cc = i&31;
            As[r][cc] = toF(A[(size_t)(m0+r)*K + k0 + cc]);
        }
        for (int i=tid; i<32*64; i+=256){
            int r = i>>6, cc = i&63; int col = n0+cc;
            Bs[r][cc] = (col < N) ? toF(Bw[(size_t)(k0+r)*ldb + col]) : 0.f;
        }
        __syncthreads();
        #pragma unroll 8
        for (int k=0;k<32;k++){
            float a4[4], b4[4];
            #pragma unroll
            for (int i=0;i<4;i++) a4[i] = As[ty*4+i][k];
            #pragma unroll
            for (int j=0;j<4;j++) b4[j] = Bs[k][tx*4+j];
            #pragma unroll
            for (int i=0;i<4;i++)
                #pragma unroll
                for (int j=0;j<4;j++) acc[i][j] += a4[i]*b4[j];
        }
        __syncthreads();
    }
    #pragma unroll
    for (int i=0;i<4;i++){
        int m = m0 + ty*4 + i;
        #pragma unroll
        for (int j=0;j<4;j++){
            int n = n0 + tx*4 + j;
            if (n >= N) continue;
            float x = acc[i][j];
            if (ACT==1) x = 1.f/(1.f + __expf(-x));
            else if (ACT==2) x = fmaxf(x, 0.f);
            if (MUL){
                int mr = gtrans ? (((m & 255) << 8) | (m >> 8)) : m;
                x *= toF(Mul[(size_t)mr*N + n]);
            }
            if (RES) Res[(size_t)(m + res_off)*N + n] += x;
            else     C[(size_t)m*N + n] = toB(x);
        }
    }
}

// ---------------- attention v3: lane-per-query, register flash softmax ----------------
template<int BIAS, int L, int NW>
__global__ __launch_bounds__(NW*64) void attn3_k(bf16* __restrict__ QO,
                                                 const bf16* __restrict__ Kp, const bf16* __restrict__ Vp,
                                                 const float* __restrict__ bias,
                                                 int H, int sO, int sL){
    __shared__ float Kt[L*32];
    __shared__ float Vt[L*32];
    const int o = blockIdx.y, h = blockIdx.x, tid = threadIdx.x;
    const int GN = H*32;
    for (int idx=tid; idx<L*16; idx+=NW*64){      // 2 bf16 per iteration
        int l = idx >> 4, c2 = (idx & 15)*2;
        size_t p = (size_t)(o*sO + l*sL)*GN + h*32 + c2;
        uint32_t kk = *(const uint32_t*)(Kp + p);
        uint32_t vv = *(const uint32_t*)(Vp + p);
        Kt[l*32 + c2]   = __uint_as_float(kk << 16);
        Kt[l*32 + c2+1] = __uint_as_float(kk & 0xFFFF0000u);
        Vt[l*32 + c2]   = __uint_as_float(vv << 16);
        Vt[l*32 + c2+1] = __uint_as_float(vv & 0xFFFF0000u);
    }
    __syncthreads();
    const int q = tid;
    size_t pq = (size_t)(o*sO + q*sL)*GN + h*32;
    float qv[32];
    {   const uint4* qp = (const uint4*)(QO + pq);   // 64B aligned
        #pragma unroll
        for (int i=0;i<4;i++){
            uint4 r = qp[i];
            uint32_t u0=r.x,u1=r.y,u2=r.z,u3=r.w;
            qv[i*8+0]=__uint_as_float(u0<<16); qv[i*8+1]=__uint_as_float(u0&0xFFFF0000u);
            qv[i*8+2]=__uint_as_float(u1<<16); qv[i*8+3]=__uint_as_float(u1&0xFFFF0000u);
            qv[i*8+4]=__uint_as_float(u2<<16); qv[i*8+5]=__uint_as_float(u2&0xFFFF0000u);
            qv[i*8+6]=__uint_as_float(u3<<16); qv[i*8+7]=__uint_as_float(u3&0xFFFF0000u);
        }
    }
    float Os[32], Ob[32];
    #pragma unroll
    for (int c=0;c<32;c++){ Os[c]=0.f; Ob[c]=0.f; }
    float lsum = 0.f;
    const float* bp = (BIAS==1) ? (bias + (size_t)h*65536 + q)
                    : (BIAS==2) ? (bias + ((size_t)(o*H+h))*256) : (const float*)nullptr;
    for (int k=0;k<L;k++){
        float s = 0.f;
        #pragma unroll
        for (int c=0;c<32;c++) s += qv[c]*Kt[k*32+c];
        float e = __expf(s * 0.17677669529663687f);   // 1/sqrt(32) folded into exp arg
        lsum += e;
        #pragma unroll
        for (int c=0;c<32;c++) Os[c] += e*Vt[k*32+c];
        if (BIAS){
            float bv = (BIAS==1) ? bp[(size_t)k*256] : bp[k];
            #pragma unroll
            for (int c=0;c<32;c++) Ob[c] += bv*Vt[k*32+c];
        }
    }
    float inv = 1.f/lsum;
    #pragma unroll
    for (int c=0;c<32;c++)
        QO[pq + c] = toB(Os[c]*inv + (BIAS ? Ob[c] : 0.f));
}

// ---------------- elementwise: a *= sigmoid(g) ----------------
__global__ void mulsig_k(bf16* __restrict__ a, const bf16* __restrict__ g, int n){
    int i = blockIdx.x*256 + threadIdx.x;
    if (i < n){
        float sg = 1.f/(1.f + __expf(-toF(g[i])));
        a[i] = toB(toF(a[i]) * sg);
    }
}

// ---------------- outer product einsum, chunked over r (32 r's per chunk) ----------------
__global__ __launch_bounds__(256) void outer_k(const bf16* __restrict__ ap, const bf16* __restrict__ bp,
                                               bf16* __restrict__ outc, int r0){
    int t = blockIdx.x, rl = blockIdx.y, r = r0 + rl;
    __shared__ float As[128*32], Bs[128*32];
    for (int idx=threadIdx.x; idx<128*32; idx+=256){
        int s = idx>>5, c = idx&31;
        As[idx] = toF(ap[((size_t)s*256 + r)*32 + c]);
        Bs[idx] = toF(bp[((size_t)s*256 + t)*32 + c]);
    }
    __syncthreads();
    int ce0 = threadIdx.x*4;
    int c = ce0 >> 5, e0 = ce0 & 31;
    float acc[4] = {0.f,0.f,0.f,0.f};
    for (int s=0;s<128;s++){
        float av = As[s*32 + c];
        #pragma unroll
        for (int j=0;j<4;j++) acc[j] += av*Bs[s*32 + e0 + j];
    }
    size_t row = (size_t)rl*256 + t;
    #pragma unroll
    for (int j=0;j<4;j++) outc[row*1024 + ce0 + j] = toB(acc[j]);
}

// ================= host =================
// GEMM-B weight shapes (K,N) for transpose staging; false => plain staging
static bool tshape(int i, int& K, int& N){
    switch(i){
        case 6: case 8: case 12: case 14: K=256; N=256;  return true;   // msa gate/out
        case 7: case 13:                  K=256; N=768;  return true;   // msa qkv
        case 17:                          K=256; N=1024; return true;   // mt_p1
        case 18:                          K=1024;N=256;  return true;   // mt_p2
        case 23:                          K=1024;N=128;  return true;   // outer_out
        case 47: case 53:                 K=128; N=384;  return true;   // tri qkv
        case 58:                          K=128; N=512;  return true;   // pt_p1
        case 59:                          K=512; N=128;  return true;   // pt_p2
        default:
            if ((i>=28&&i<=33)||(i>=38&&i<=43)||i==46||i==48||i==52||i==54){ K=128; N=128; return true; }
            return false;
    }
}

extern "C" void kernel_launch(void* const* d_in, const int* in_sizes, int n_in,
                              void* d_out, int out_size, void* d_ws, size_t ws_size,
                              hipStream_t stream){
    (void)n_in; (void)out_size; (void)ws_size;
    const int MSA_N  = 128*256*256;   // 8388608
    const int PAIR_N = 256*256*128;   // 8388608
    const uint32_t* probe = (const uint32_t*)d_in[2];   // row_norm_m_w = ones

    // ---- workspace layout: 70 MB ----
    char*  w     = (char*)d_ws;
    bf16*  wsts  = (bf16*)(w);                 // [0, 4MB) staged bf16 weights (GEMM ones transposed)
    float* biasF = (float*)(w + 4194304);      // [4MB, 6MB)
    bf16*  lnb   = (bf16*)(w + 6291456);       // [6MB, 22MB)
    bf16*  bufA  = (bf16*)(w + 23068672);      // [22MB, 38MB)
    bf16*  bufB  = (bf16*)(w + 39845888);      // [38MB, 54MB)
    bf16*  bufC  = (bf16*)(w + 56623104);      // [54MB, 70MB)

    float* msaF  = (float*)d_out;              // f32 msa accumulator == output 0
    float* pairF = msaF + MSA_N;               // f32 pair accumulator == output 1

    // ---- stage all weights (inputs 2..59) to bf16; GEMM weights transposed ----
    size_t woff[64]; { size_t acc = 0;
        for (int i=2;i<60;i++){ woff[i] = acc; acc += ((size_t)in_sizes[i] + 63) & ~(size_t)63; } }
    #define W(i) (wsts + woff[i])
    for (int i=2;i<60;i++){
        int tk, tn;
        if (tshape(i, tk, tn))
            cvt_wT_k<<<(in_sizes[i]+255)/256,256,0,stream>>>(d_in[i], W(i), tk, tn, probe);
        else
            cvt_w_k<<<(in_sizes[i]+255)/256,256,0,stream>>>(d_in[i], W(i), in_sizes[i], probe);
    }

    in2f_k<<<32768,256,0,stream>>>(d_in[0], msaF,  MSA_N,  probe);
    in2f_k<<<32768,256,0,stream>>>(d_in[1], pairF, PAIR_N, probe);

    #define GEMM_GRID(M,N) dim3(((N)+63)/64, (M)/64)
    #define MG(M,N)        dim3((N)/128, (M)/128)

    // ================= Row attention (bias = LN(pair)@row_bias, post-softmax) =================
    ln_k<float><<<32768,256,0,stream>>>(msaF, W(2), W(3), lnb, 256);
    ln_bias_k<<<65536,128,0,stream>>>(pairF, W(4), W(5), W(9), biasF, 8, 0);
    mgemm_k<0,0,0><<<MG(32768,256),256,0,stream>>>(lnb, W(7),        bufA, nullptr, nullptr, 32768,256,256, 256, 0,0); // Q
    mgemm_k<0,0,0><<<MG(32768,256),256,0,stream>>>(lnb, W(7)+65536,  bufB, nullptr, nullptr, 32768,256,256, 256, 0,0); // K
    mgemm_k<0,0,0><<<MG(32768,256),256,0,stream>>>(lnb, W(7)+131072, bufC, nullptr, nullptr, 32768,256,256, 256, 0,0); // V
    attn3_k<1,256,4><<<dim3(8,128),256,0,stream>>>(bufA, bufB, bufC, biasF, 8, 256, 1);
    mgemm_k<0,0,0><<<MG(32768,256),256,0,stream>>>(lnb, W(6), bufB, nullptr, nullptr, 32768,256,256, 256, 0,0);        // gate raw
    mulsig_k<<<32768,256,0,stream>>>(bufA, bufB, MSA_N);
    mgemm_k<0,0,1><<<MG(32768,256),256,0,stream>>>(bufA, W(8), nullptr, msaF, nullptr, 32768,256,256, 256, 0,0);

    // ================= Column attention (attend over s, L=128, no bias) =================
    ln_k<float><<<32768,256,0,stream>>>(msaF, W(10), W(11), lnb, 256);
    mgemm_k<0,0,0><<<MG(32768,256),256,0,stream>>>(lnb, W(13),        bufA, nullptr, nullptr, 32768,256,256, 256, 0,0);
    mgemm_k<0,0,0><<<MG(32768,256),256,0,stream>>>(lnb, W(13)+65536,  bufB, nullptr, nullptr, 32768,256,256, 256, 0,0);
    mgemm_k<0,0,0><<<MG(32768,256),256,0,stream>>>(lnb, W(13)+131072, bufC, nullptr, nullptr, 32768,256,256, 256, 0,0);
    attn3_k<0,128,2><<<dim3(8,256),128,0,stream>>>(bufA, bufB, bufC, nullptr, 8, 1, 256);
    mgemm_k<0,0,0><<<MG(32768,256),256,0,stream>>>(lnb, W(12), bufB, nullptr, nullptr, 32768,256,256, 256, 0,0);
    mulsig_k<<<32768,256,0,stream>>>(bufA, bufB, MSA_N);
    mgemm_k<0,0,1><<<MG(32768,256),256,0,stream>>>(bufA, W(14), nullptr, msaF, nullptr, 32768,256,256, 256, 0,0);

    // ================= MSA transition (FF chunked 4 x 256) =================
    ln_k<float><<<32768,256,0,stream>>>(msaF, W(15), W(16), lnb, 256);
    for (int ch=0; ch<4; ++ch){
        mgemm_k<2,0,0><<<MG(32768,256),256,0,stream>>>(lnb, W(17)+ch*65536, bufA, nullptr, nullptr, 32768,256,256, 256, 0,0);
        mgemm_k<0,0,1><<<MG(32768,256),256,0,stream>>>(bufA, W(18)+ch*256, nullptr, msaF, nullptr, 32768,256,256, 1024, 0,0);
    }

    // ================= Outer product mean (chunked 8 x 32 r's; chunks reuse lnb) =================
    ln_k<float><<<32768,256,0,stream>>>(msaF, W(19), W(20), lnb, 256);
    gemm_k<0,0,0><<<GEMM_GRID(32768,32),256,0,stream>>>(lnb, W(21), bufA, nullptr, nullptr, 32768,32,256, 32, 0,0);
    gemm_k<0,0,0><<<GEMM_GRID(32768,32),256,0,stream>>>(lnb, W(22), bufB, nullptr, nullptr, 32768,32,256, 32, 0,0);
    for (int ch=0; ch<8; ++ch){   // lnb dead; reuse as 8192x1024 chunk buffer
        outer_k<<<dim3(256,32),256,0,stream>>>(bufA, bufB, lnb, ch*32);
        mgemm_k<0,0,1><<<MG(8192,128),256,0,stream>>>(lnb, W(23), nullptr, pairF, nullptr, 8192,128,1024, 1024, ch*8192,0);
    }

    // ================= Triangle mult outgoing / incoming (MFMA batched GEMM over k) =================
    for (int tm=0; tm<2; ++tm){
        int o = tm ? 34 : 24;   // tmi_* : tmo_*
        int inc = tm;
        ln_k<float><<<65536,128,0,stream>>>(pairF, W(o+0), W(o+1), lnb, 128);
        mgemm_k<1,0,0><<<MG(65536,128),256,0,stream>>>(lnb, W(o+4), bufA, nullptr, nullptr, 65536,128,128, 128, 0,0); // sig(xn@p1)
        mgemm_k<0,1,0><<<MG(65536,128),256,0,stream>>>(lnb, W(o+5), bufA, nullptr, bufA,   65536,128,128, 128, 0,0); // a
        mgemm_k<1,0,0><<<MG(65536,128),256,0,stream>>>(lnb, W(o+6), bufB, nullptr, nullptr, 65536,128,128, 128, 0,0); // sig(xn@p3)
        mgemm_k<0,1,0><<<MG(65536,128),256,0,stream>>>(lnb, W(o+7), bufB, nullptr, bufB,   65536,128,128, 128, 0,0); // b
        rc2k_k<<<512,256,0,stream>>>(bufA, bufC, inc);                  // aT -> bufC (a dead after)
        rc2k_k<<<512,256,0,stream>>>(bufB, bufA, inc);                  // bT -> bufA (b dead after)
        btrimul_k<<<dim3(2,2,128),256,0,stream>>>(bufC, bufA, bufB);    // pT -> bufB
        k2rc_k<<<512,256,0,stream>>>(bufB, bufC);                       // p [s*256+t][k] -> bufC
        ln_k<bf16><<<65536,128,0,stream>>>(bufC, W(o+2), W(o+3), bufC, 128);  // LN(p) in place
        mgemm_k<1,0,0><<<MG(65536,128),256,0,stream>>>(lnb, W(o+9), bufA, nullptr, nullptr, 65536,128,128, 128, 0,0); // g (lnb intact)
        mgemm_k<0,1,1><<<MG(65536,128),256,0,stream>>>(bufC, W(o+8), nullptr, pairF, bufA, 65536,128,128, 128, 0, inc);
    }

    // ================= Triangle attention starting (tas) =================
    ln_k<float><<<65536,128,0,stream>>>(pairF, W(44), W(45), lnb, 128);
    ln_bias_k<<<65536,128,0,stream>>>(pairF, W(44), W(45), W(49), biasF, 4, 1);
    mgemm_k<0,0,0><<<MG(65536,128),256,0,stream>>>(lnb, W(47),       bufA, nullptr, nullptr, 65536,128,128, 128, 0,0);
    mgemm_k<0,0,0><<<MG(65536,128),256,0,stream>>>(lnb, W(47)+16384, bufB, nullptr, nullptr, 65536,128,128, 128, 0,0);
    mgemm_k<0,0,0><<<MG(65536,128),256,0,stream>>>(lnb, W(47)+32768, bufC, nullptr, nullptr, 65536,128,128, 128, 0,0);
    attn3_k<2,256,4><<<dim3(4,256),256,0,stream>>>(bufA, bufB, bufC, biasF, 4, 256, 1);
    mgemm_k<0,0,0><<<MG(65536,128),256,0,stream>>>(lnb, W(46), bufB, nullptr, nullptr, 65536,128,128, 128, 0,0);
    mulsig_k<<<32768,256,0,stream>>>(bufA, bufB, PAIR_N);
    mgemm_k<0,0,1><<<MG(65536,128),256,0,stream>>>(bufA, W(48), nullptr, pairF, nullptr, 65536,128,128, 128, 0,0);

    // ================= Triangle attention ending (tae) =================
    ln_k<float><<<65536,128,0,stream>>>(pairF, W(50), W(51), lnb, 128);
    ln_bias_k<<<65536,128,0,stream>>>(pairF, W(50), W(51), W(55), biasF, 4, 2);
    mgemm_k<0,0,0><<<MG(65536,128),256,0,stream>>>(lnb, W(53),       bufA, nullptr, nullptr, 65536,128,128, 128, 0,0);
    mgemm_k<0,0,0><<<MG(65536,128),256,0,stream>>>(lnb, W(53)+16384, bufB, nullptr, nullptr, 65536,128,128, 128, 0,0);
    mgemm_k<0,0,0><<<MG(65536,128),256,0,stream>>>(lnb, W(53)+32768, bufC, nullptr, nullptr, 65536,128,128, 128, 0,0);
    attn3_k<2,256,4><<<dim3(4,256),256,0,stream>>>(bufA, bufB, bufC, biasF, 4, 1, 256);
    mgemm_k<0,0,0><<<MG(65536,128),256,0,stream>>>(lnb, W(52), bufB, nullptr, nullptr, 65536,128,128, 128, 0,0);
    mulsig_k<<<32768,256,0,stream>>>(bufA, bufB, PAIR_N);
    mgemm_k<0,0,1><<<MG(65536,128),256,0,stream>>>(bufA, W(54), nullptr, pairF, nullptr, 65536,128,128, 128, 0,0);

    // ================= Pair transition (FF chunked 4 x 128) =================
    ln_k<float><<<65536,128,0,stream>>>(pairF, W(56), W(57), lnb, 128);
    for (int ch=0; ch<4; ++ch){
        mgemm_k<2,0,0><<<MG(65536,128),256,0,stream>>>(lnb, W(58)+ch*16384, bufA, nullptr, nullptr, 65536,128,128, 128, 0,0);
        mgemm_k<0,0,1><<<MG(65536,128),256,0,stream>>>(bufA, W(59)+ch*128, nullptr, pairF, nullptr, 65536,128,128, 512, 0,0);
    }
    // outputs are msaF/pairF in d_out (f32) — done.
}

// Round 3
// 2683.684 us; speedup vs baseline: 1.4842x; 1.1815x over previous
//
#include <hip/hip_runtime.h>
#include <hip/hip_bf16.h>
#include <stdint.h>

typedef __hip_bfloat16 bf16;
typedef __attribute__((ext_vector_type(4))) int   i32x4;
typedef __attribute__((ext_vector_type(4))) float f32x4;

// Shapes (N=1): S=128, R=256, CM=256, CZ=128, C=32, MSA_H=8, PAIR_H=4, CTM=128, FF=4
// msa rows: s*256+r (32768 x 256); pair rows: i*256+j (65536 x 128)
// I/O dtype: FLOAT32. Accumulators f32 live directly in d_out (they ARE the outputs).
// Workspace (70 MB): weights 4MB | biasF 2MB | lnb 16MB | bufA 16MB | bufB 16MB | bufC 16MB.
// GEMM weights are staged TRANSPOSED (W^T [N][K]) so MFMA B-fragments read k-contiguous bf16x8.

__device__ __forceinline__ float toF(float x){ return x; }
__device__ __forceinline__ float toF(bf16 x){ return __bfloat162float(x); }
__device__ __forceinline__ bf16  toB(float x){ return __float2bfloat16(x); }

__device__ __forceinline__ void gload16(const bf16* g, bf16* l){
    __builtin_amdgcn_global_load_lds((const __attribute__((address_space(1))) void*)g,
                                     (__attribute__((address_space(3))) void*)l, 16, 0, 0);
}

// ---------------- input staging (dtype probe: bf16 ones -> 0x3F803F80, f32 one -> 0x3F800000) ----------------
__global__ void cvt_w_k(const void* __restrict__ in, bf16* __restrict__ out, int n,
                        const uint32_t* __restrict__ probe){
    bool isbf = (probe[0] == 0x3F803F80u);
    int i = blockIdx.x*256 + threadIdx.x;
    if (i < n) out[i] = isbf ? ((const bf16*)in)[i] : toB(((const float*)in)[i]);
}
// transpose-staging for GEMM B operands: in [K][N] row-major -> out [N][K] row-major
__global__ void cvt_wT_k(const void* __restrict__ in, bf16* __restrict__ out, int K, int N,
                         const uint32_t* __restrict__ probe){
    bool isbf = (probe[0] == 0x3F803F80u);
    int i = blockIdx.x*256 + threadIdx.x;
    if (i < K*N){
        float v = isbf ? toF(((const bf16*)in)[i]) : ((const float*)in)[i];
        int k = i / N, n = i - k*N;
        out[(size_t)n*K + k] = toB(v);
    }
}
__global__ void in2f_k(const void* __restrict__ in, float* __restrict__ out, int n,
                       const uint32_t* __restrict__ probe){
    bool isbf = (probe[0] == 0x3F803F80u);
    int i = blockIdx.x*256 + threadIdx.x;
    if (i < n) out[i] = isbf ? toF(((const bf16*)in)[i]) : ((const float*)in)[i];
}

// ---------------- LayerNorm: one block per row, blockDim = D (128 or 256); in-place safe ----------------
template<typename T>
__global__ void ln_k(const T* __restrict__ x, const bf16* __restrict__ w, const bf16* __restrict__ b,
                     bf16* __restrict__ out, int D){
    int row = blockIdx.x, c = threadIdx.x;
    float v = toF(x[(size_t)row*D + c]);
    float s1 = v, s2 = v*v;
    #pragma unroll
    for (int o=32;o>0;o>>=1){ s1 += __shfl_down(s1,o); s2 += __shfl_down(s2,o); }
    __shared__ float r1[4], r2[4];
    int lane = c & 63, wid = c >> 6;
    if (lane==0){ r1[wid]=s1; r2[wid]=s2; }
    __syncthreads();
    int nw = blockDim.x >> 6;
    float m=0.f, q=0.f;
    for (int i=0;i<nw;i++){ m+=r1[i]; q+=r2[i]; }
    m /= (float)D; q = q/(float)D - m*m;
    float inv = rsqrtf(q + 1e-5f);
    out[(size_t)row*D + c] = toB((v-m)*inv*toF(w[c]) + toF(b[c]));
}

// ---------------- fused LN + attention-bias projection (reads f32 pair acc) ----------------
__global__ void ln_bias_k(const float* __restrict__ pairf, const bf16* __restrict__ w, const bf16* __restrict__ b,
                          const bf16* __restrict__ Wb, float* __restrict__ outb, int Hn, int mode){
    int pp = blockIdx.x, c = threadIdx.x;           // 128 threads
    int i = pp >> 8, j = pp & 255;
    float v = pairf[(size_t)pp*128 + c];
    float s1 = v, s2 = v*v;
    #pragma unroll
    for (int o=32;o>0;o>>=1){ s1 += __shfl_down(s1,o); s2 += __shfl_down(s2,o); }
    __shared__ float r1[2], r2[2], rh[2];
    int lane = c & 63, wid = c >> 6;
    if (lane==0){ r1[wid]=s1; r2[wid]=s2; }
    __syncthreads();
    float m = (r1[0]+r1[1])*(1.f/128.f);
    float q = (r2[0]+r2[1])*(1.f/128.f) - m*m;
    float xn = (v-m)*rsqrtf(q+1e-5f)*toF(w[c]) + toF(b[c]);
    for (int h=0; h<Hn; ++h){
        float p = xn*toF(Wb[c*Hn + h]);
        #pragma unroll
        for (int o=32;o>0;o>>=1) p += __shfl_down(p,o);
        if (lane==0) rh[wid]=p;
        __syncthreads();
        if (c==0){
            float sv = rh[0]+rh[1];
            size_t idx = (mode==0) ? ((size_t)(h*256+j)*256 + i)
                       : (mode==1) ? ((size_t)(i*Hn+h)*256 + j)
                                   : ((size_t)(j*Hn+h)*256 + i);
            outb[idx] = sv;
        }
        __syncthreads();
    }
}

// ---------------- MFMA GEMM (bf16 in, f32 accum): C[M][N] = A[M][K] @ B, B given as B^T [N][K] ----------------
template<int ACT, int MUL, int RES>
__global__ __launch_bounds__(256) void mgemm_k(const bf16* __restrict__ A, const bf16* __restrict__ Bt,
                                               bf16* __restrict__ C, float* __restrict__ Res,
                                               const bf16* __restrict__ Mul,
                                               int M, int N, int K, int ldbt, int res_off, int gtrans){
    __shared__ alignas(16) bf16 As[128*32];
    __shared__ alignas(16) bf16 Bs[128*32];
    const int tid  = threadIdx.x;
    const int m0   = blockIdx.y << 7, n0 = blockIdx.x << 7;
    const int lane = tid & 63, w = tid >> 6;
    const int wr   = (w >> 1) << 6, wc = (w & 1) << 6;
    const int fr   = lane & 15, fq = lane >> 4;
    const int sr = tid >> 2, sc = (tid & 3) << 3;
    const bf16* ga = A  + (size_t)(m0 + sr)*K    + sc;
    const bf16* gb = Bt + (size_t)(n0 + sr)*ldbt + sc;
    bf16* la = As + tid*8;
    bf16* lb = Bs + tid*8;
    const size_t gaS = (size_t)64*K, gbS = (size_t)64*ldbt;

    f32x4 acc[4][4] = {};
    for (int k0=0; k0<K; k0+=32){
        gload16(ga, la);        gload16(ga + gaS, la + 2048);
        gload16(gb, lb);        gload16(gb + gbS, lb + 2048);
        ga += 32; gb += 32;
        __syncthreads();
        i32x4 af[4], bv[4];
        #pragma unroll
        for (int i=0;i<4;i++) af[i] = *(const i32x4*)(As + ((wr + i*16 + fr) << 5) + (fq << 3));
        #pragma unroll
        for (int j=0;j<4;j++) bv[j] = *(const i32x4*)(Bs + ((wc + j*16 + fr) << 5) + (fq << 3));
        #pragma unroll
        for (int i=0;i<4;i++)
            #pragma unroll
            for (int j=0;j<4;j++)
                asm("v_mfma_f32_16x16x32_bf16 %0, %1, %2, %0"
                    : "+v"(acc[i][j]) : "v"(af[i]), "v"(bv[j]));
        __syncthreads();
    }
    #pragma unroll
    for (int i=0;i<4;i++){
        const int mB = m0 + wr + i*16 + (fq << 2);
        #pragma unroll
        for (int j=0;j<4;j++){
            const int n = n0 + wc + j*16 + fr;
            #pragma unroll
            for (int r=0;r<4;r++){
                int m = mB + r;
                float x = acc[i][j][r];
                if (ACT==1) x = 1.f/(1.f + __expf(-x));
                else if (ACT==2) x = fmaxf(x, 0.f);
                if (MUL){
                    int mr = gtrans ? (((m & 255) << 8) | (m >> 8)) : m;
                    x *= toF(Mul[(size_t)mr*N + n]);
                }
                if (RES) Res[(size_t)(m + res_off)*N + n] += x;
                else     C[(size_t)m*N + n] = toB(x);
            }
        }
    }
}

// ---------------- batched MFMA GEMM for triangle mult: per-k C_k = A_k @ B_k^T (256x256x256) ----------------
__global__ __launch_bounds__(256) void btrimul_k(const bf16* __restrict__ aT, const bf16* __restrict__ bT,
                                                 bf16* __restrict__ pT){
    __shared__ alignas(16) bf16 As[128*32];
    __shared__ alignas(16) bf16 Bs[128*32];
    const int tid  = threadIdx.x;
    const int m0   = blockIdx.y << 7, n0 = blockIdx.x << 7;
    const size_t zb = (size_t)blockIdx.z << 16;           // k*65536
    const int lane = tid & 63, w = tid >> 6;
    const int wr   = (w >> 1) << 6, wc = (w & 1) << 6;
    const int fr   = lane & 15, fq = lane >> 4;
    const int sr = tid >> 2, sc = (tid & 3) << 3;
    const bf16* ga = aT + zb + (size_t)(m0 + sr)*256 + sc;
    const bf16* gb = bT + zb + (size_t)(n0 + sr)*256 + sc;
    bf16* la = As + tid*8;
    bf16* lb = Bs + tid*8;
    const size_t gS = (size_t)64*256;

    f32x4 acc[4][4] = {};
    for (int k0=0; k0<256; k0+=32){
        gload16(ga, la);        gload16(ga + gS, la + 2048);
        gload16(gb, lb);        gload16(gb + gS, lb + 2048);
        ga += 32; gb += 32;
        __syncthreads();
        i32x4 af[4], bv[4];
        #pragma unroll
        for (int i=0;i<4;i++) af[i] = *(const i32x4*)(As + ((wr + i*16 + fr) << 5) + (fq << 3));
        #pragma unroll
        for (int j=0;j<4;j++) bv[j] = *(const i32x4*)(Bs + ((wc + j*16 + fr) << 5) + (fq << 3));
        #pragma unroll
        for (int i=0;i<4;i++)
            #pragma unroll
            for (int j=0;j<4;j++)
                asm("v_mfma_f32_16x16x32_bf16 %0, %1, %2, %0"
                    : "+v"(acc[i][j]) : "v"(af[i]), "v"(bv[j]));
        __syncthreads();
    }
    #pragma unroll
    for (int i=0;i<4;i++){
        const int mB = m0 + wr + i*16 + (fq << 2);
        #pragma unroll
        for (int j=0;j<4;j++){
            const int n = n0 + wc + j*16 + fr;
            #pragma unroll
            for (int r=0;r<4;r++)
                pT[zb + (size_t)(mB + r)*256 + n] = toB(acc[i][j][r]);
        }
    }
}

// ---------------- row/channel transposes for triangle mult ----------------
__global__ __launch_bounds__(256) void rc2k_k(const bf16* __restrict__ in, bf16* __restrict__ out, int swap){
    __shared__ uint16_t T[128][137];
    const int tt = blockIdx.x, tid = threadIdx.x;
    size_t base_pp, out_off; int ppstride;
    if (!swap){ base_pp = (size_t)tt*128;                  ppstride = 1;   out_off = (size_t)tt*128; }
    else      { int J = tt>>1, I0 = (tt&1)*128;
                base_pp = (size_t)I0*256 + J;              ppstride = 256; out_off = (size_t)J*256 + I0; }
    for (int it=0; it<8; ++it){
        int idx = tid + it*256;                 // [0,2048): 16B chunks
        int r = idx >> 4, c8 = (idx & 15) << 3;
        uint4 v = *(const uint4*)(in + (base_pp + (size_t)r*ppstride)*128 + c8);
        uint16_t tmp[8]; *(uint4*)tmp = v;
        #pragma unroll
        for (int t=0;t<8;t++) T[r][c8+t] = tmp[t];
    }
    __syncthreads();
    for (int it=0; it<8; ++it){
        int idx = tid + it*256;
        int k = idx >> 4, r8 = (idx & 15) << 3;
        uint16_t tmp[8];
        #pragma unroll
        for (int t=0;t<8;t++) tmp[t] = T[r8+t][k];
        *(uint4*)(out + (size_t)k*65536 + out_off + r8) = *(uint4*)tmp;
    }
}
__global__ __launch_bounds__(256) void k2rc_k(const bf16* __restrict__ in, bf16* __restrict__ out){
    __shared__ uint16_t T[128][137];
    const int tt = blockIdx.x, tid = threadIdx.x;
    const size_t a0 = (size_t)tt*128;
    for (int it=0; it<8; ++it){
        int idx = tid + it*256;
        int k = idx >> 4, r8 = (idx & 15) << 3;
        uint4 v = *(const uint4*)(in + (size_t)k*65536 + a0 + r8);
        uint16_t tmp[8]; *(uint4*)tmp = v;
        #pragma unroll
        for (int t=0;t<8;t++) T[r8+t][k] = tmp[t];
    }
    __syncthreads();
    for (int it=0; it<8; ++it){
        int idx = tid + it*256;
        int r = idx >> 4, c8 = (idx & 15) << 3;
        uint16_t tmp[8];
        #pragma unroll
        for (int t=0;t<8;t++) tmp[t] = T[r][c8+t];
        *(uint4*)(out + (a0 + r)*128 + c8) = *(uint4*)tmp;
    }
}

// ---------------- legacy VALU GEMM (kept only for N=32 outer projections) ----------------
template<int ACT, int MUL, int RES>
__global__ __launch_bounds__(256) void gemm_k(const bf16* __restrict__ A, const bf16* __restrict__ Bw,
                                              bf16* __restrict__ C, float* __restrict__ Res,
                                              const bf16* __restrict__ Mul,
                                              int M, int N, int K, int ldb, int res_off, int gtrans){
    __shared__ float As[64][33];
    __shared__ float Bs[32][65];
    int tid = threadIdx.x;
    int m0 = blockIdx.y*64, n0 = blockIdx.x*64;
    int tx = tid & 15, ty = tid >> 4;
    float acc[4][4] = {};
    for (int k0=0; k0<K; k0+=32){
        for (int i=tid; i<64*32; i+=256){
            int r = i>>5, cc = i&31;
            As[r][cc] = toF(A[(size_t)(m0+r)*K + k0 + cc]);
        }
        for (int i=tid; i<32*64; i+=256){
            int r = i>>6, cc = i&63; int col = n0+cc;
            Bs[r][cc] = (col < N) ? toF(Bw[(size_t)(k0+r)*ldb + col]) : 0.f;
        }
        __syncthreads();
        #pragma unroll 8
        for (int k=0;k<32;k++){
            float a4[4], b4[4];
            #pragma unroll
            for (int i=0;i<4;i++) a4[i] = As[ty*4+i][k];
            #pragma unroll
            for (int j=0;j<4;j++) b4[j] = Bs[k][tx*4+j];
            #pragma unroll
            for (int i=0;i<4;i++)
                #pragma unroll
                for (int j=0;j<4;j++) acc[i][j] += a4[i]*b4[j];
        }
        __syncthreads();
    }
    #pragma unroll
    for (int i=0;i<4;i++){
        int m = m0 + ty*4 + i;
        #pragma unroll
        for (int j=0;j<4;j++){
            int n = n0 + tx*4 + j;
            if (n >= N) continue;
            float x = acc[i][j];
            if (ACT==1) x = 1.f/(1.f + __expf(-x));
            else if (ACT==2) x = fmaxf(x, 0.f);
            if (MUL){
                int mr = gtrans ? (((m & 255) << 8) | (m >> 8)) : m;
                x *= toF(Mul[(size_t)mr*N + n]);
            }
            if (RES) Res[(size_t)(m + res_off)*N + n] += x;
            else     C[(size_t)m*N + n] = toB(x);
        }
    }
}

// ---------------- attention v4: MFMA flash attention ----------------
// One block per (h, o): 256 threads = 4 waves, wave w owns queries [w*MW, (w+1)*MW).
// K staged [L][40] bf16; V staged transposed [32][L+8]; P in wave-private LDS (no barrier in k-loop).
// Softmax without max-subtraction (scores LN-bounded) — same math as verified VALU version.
// BIAS 0: none. BIAS 1 (row attn, L=256): O += (bias@V), bias[(h*256+k)*256+q], staged per chunk.
// BIAS 2 (tri attn): bias[(o*H+h)*256+k] q-uniform -> rank-1 Ob[c] computed once.
template<int BIAS, int L>
__global__ __launch_bounds__(256) void attn4_k(bf16* __restrict__ QO,
                                               const bf16* __restrict__ Kp, const bf16* __restrict__ Vp,
                                               const float* __restrict__ bias,
                                               int H, int sO, int sL){
    constexpr int MW  = L/4;       // queries per wave
    constexpr int IFR = MW/16;     // m-fragments per wave
    constexpr int KC  = 32;        // key chunk (one MFMA k-step)
    constexpr int NCH = L/KC;
    constexpr int VP  = L + 8;     // VT row pad (elems); row bytes multiple of 16
    __shared__ alignas(16) bf16 K_lds[L*40];
    __shared__ alignas(16) bf16 VT_lds[32*VP];
    __shared__ alignas(16) bf16 P_lds[L*40];      // 4 waves x MW x 40
    __shared__ float red[8*32 + 32];
    const int o = blockIdx.y, h = blockIdx.x, tid = threadIdx.x;
    const int GN = H*32;
    const int lane = tid & 63, w = tid >> 6;
    const int fr = lane & 15, fq = lane >> 4;

    // ---- stage K rows + V transposed ----
    for (int idx = tid; idx < L*4; idx += 256){
        int l = idx >> 2, c8 = (idx & 3) << 3;
        size_t p = (size_t)(o*sO + l*sL)*GN + h*32 + c8;
        *(uint4*)(K_lds + l*40 + c8) = *(const uint4*)(Kp + p);
        uint4 vv = *(const uint4*)(Vp + p);
        bf16 tmp[8]; *(uint4*)tmp = vv;
        #pragma unroll
        for (int t=0;t<8;t++) VT_lds[(c8+t)*VP + l] = tmp[t];
    }
    __syncthreads();

    float* ObS = red + 256;
    if (BIAS == 2){
        int c = tid & 31, g = tid >> 5;
        const float* bp = bias + (size_t)(o*H + h)*256;
        float p = 0.f;
        for (int k = g*(L/8); k < (g+1)*(L/8); ++k)
            p += bp[k] * toF(VT_lds[c*VP + k]);
        red[g*32 + c] = p;
        __syncthreads();
        if (tid < 32){
            float s = 0.f;
            #pragma unroll
            for (int g2=0; g2<8; ++g2) s += red[g2*32 + tid];
            ObS[tid] = s;
        }
        __syncthreads();
    }

    // ---- Q fragments (once, from global) ----
    i32x4 qf[IFR];
    #pragma unroll
    for (int i=0;i<IFR;i++){
        int q = w*MW + i*16 + fr;
        qf[i] = *(const i32x4*)(QO + (size_t)(o*sO + q*sL)*GN + h*32 + fq*8);
    }
    bf16* Pw = P_lds + w*MW*40;
    f32x4 accO[IFR][2] = {};
    f32x4 accB[IFR][2] = {};
    float lsum[IFR][4] = {};

    for (int ch=0; ch<NCH; ++ch){
        const int k0 = ch*KC;
        // S = Q @ K^T for this key chunk
        f32x4 sa[IFR][2] = {};
        i32x4 kf[2];
        #pragma unroll
        for (int j=0;j<2;j++) kf[j] = *(const i32x4*)(K_lds + (k0 + j*16 + fr)*40 + fq*8);
        #pragma unroll
        for (int i=0;i<IFR;i++)
            #pragma unroll
            for (int j=0;j<2;j++)
                asm("v_mfma_f32_16x16x32_bf16 %0, %1, %2, %0"
                    : "+v"(sa[i][j]) : "v"(qf[i]), "v"(kf[j]));
        // exp + lsum partials + write P (wave-private)
        #pragma unroll
        for (int i=0;i<IFR;i++)
            #pragma unroll
            for (int j=0;j<2;j++)
                #pragma unroll
                for (int r=0;r<4;r++){
                    float e = __expf(sa[i][j][r] * 0.17677669529663687f);
                    lsum[i][r] += e;
                    Pw[(i*16 + fq*4 + r)*40 + j*16 + fr] = toB(e);
                }
        // V^T fragments for this chunk (shared by E-PV and bias-PV)
        i32x4 vf[2];
        #pragma unroll
        for (int j=0;j<2;j++) vf[j] = *(const i32x4*)(VT_lds + (j*16 + fr)*VP + k0 + fq*8);
        // O += P @ V
        #pragma unroll
        for (int i=0;i<IFR;i++){
            i32x4 pa = *(const i32x4*)(Pw + (i*16 + fr)*40 + fq*8);
            #pragma unroll
            for (int j=0;j<2;j++)
                asm("v_mfma_f32_16x16x32_bf16 %0, %1, %2, %0"
                    : "+v"(accO[i][j]) : "v"(pa), "v"(vf[j]));
        }
        if (BIAS == 1){
            // stage this wave's bias sub-block (64 q rows x KC keys) into Pw, then accB += Pb @ V
            #pragma unroll 4
            for (int kl=0; kl<KC; ++kl){
                float bv = bias[(size_t)(h*256 + k0 + kl)*256 + w*MW + lane];
                Pw[lane*40 + kl] = toB(bv);
            }
            #pragma unroll
            for (int i=0;i<IFR;i++){
                i32x4 pa = *(const i32x4*)(Pw + (i*16 + fr)*40 + fq*8);
                #pragma unroll
                for (int j=0;j<2;j++)
                    asm("v_mfma_f32_16x16x32_bf16 %0, %1, %2, %0"
                        : "+v"(accB[i][j]) : "v"(pa), "v"(vf[j]));
            }
        }
    }
    // reduce lsum across the 16 fr lanes sharing each row
    #pragma unroll
    for (int i=0;i<IFR;i++)
        #pragma unroll
        for (int r=0;r<4;r++){
            float s = lsum[i][r];
            s += __shfl_xor(s, 1); s += __shfl_xor(s, 2);
            s += __shfl_xor(s, 4); s += __shfl_xor(s, 8);
            lsum[i][r] = 1.f / s;
        }
    #pragma unroll
    for (int i=0;i<IFR;i++)
        #pragma unroll
        for (int j=0;j<2;j++)
            #pragma unroll
            for (int r=0;r<4;r++){
                int q = w*MW + i*16 + fq*4 + r;
                int c = j*16 + fr;
                float v = accO[i][j][r]*lsum[i][r];
                if (BIAS==1) v += accB[i][j][r];
                if (BIAS==2) v += ObS[c];
                QO[(size_t)(o*sO + q*sL)*GN + h*32 + c] = toB(v);
            }
}

// ---------------- elementwise: a *= sigmoid(g) ----------------
__global__ void mulsig_k(bf16* __restrict__ a, const bf16* __restrict__ g, int n){
    int i = blockIdx.x*256 + threadIdx.x;
    if (i < n){
        float sg = 1.f/(1.f + __expf(-toF(g[i])));
        a[i] = toB(toF(a[i]) * sg);
    }
}

// ---------------- outer product einsum, chunked over r (32 r's per chunk) ----------------
__global__ __launch_bounds__(256) void outer_k(const bf16* __restrict__ ap, const bf16* __restrict__ bp,
                                               bf16* __restrict__ outc, int r0){
    int t = blockIdx.x, rl = blockIdx.y, r = r0 + rl;
    __shared__ float As[128*32], Bs[128*32];
    for (int idx=threadIdx.x; idx<128*32; idx+=256){
        int s = idx>>5, c = idx&31;
        As[idx] = toF(ap[((size_t)s*256 + r)*32 + c]);
        Bs[idx] = toF(bp[((size_t)s*256 + t)*32 + c]);
    }
    __syncthreads();
    int ce0 = threadIdx.x*4;
    int c = ce0 >> 5, e0 = ce0 & 31;
    float acc[4] = {0.f,0.f,0.f,0.f};
    for (int s=0;s<128;s++){
        float av = As[s*32 + c];
        #pragma unroll
        for (int j=0;j<4;j++) acc[j] += av*Bs[s*32 + e0 + j];
    }
    size_t row = (size_t)rl*256 + t;
    #pragma unroll
    for (int j=0;j<4;j++) outc[row*1024 + ce0 + j] = toB(acc[j]);
}

// ================= host =================
static bool tshape(int i, int& K, int& N){
    switch(i){
        case 6: case 8: case 12: case 14: K=256; N=256;  return true;   // msa gate/out
        case 7: case 13:                  K=256; N=768;  return true;   // msa qkv
        case 17:                          K=256; N=1024; return true;   // mt_p1
        case 18:                          K=1024;N=256;  return true;   // mt_p2
        case 23:                          K=1024;N=128;  return true;   // outer_out
        case 47: case 53:                 K=128; N=384;  return true;   // tri qkv
        case 58:                          K=128; N=512;  return true;   // pt_p1
        case 59:                          K=512; N=128;  return true;   // pt_p2
        default:
            if ((i>=28&&i<=33)||(i>=38&&i<=43)||i==46||i==48||i==52||i==54){ K=128; N=128; return true; }
            return false;
    }
}

extern "C" void kernel_launch(void* const* d_in, const int* in_sizes, int n_in,
                              void* d_out, int out_size, void* d_ws, size_t ws_size,
                              hipStream_t stream){
    (void)n_in; (void)out_size; (void)ws_size;
    const int MSA_N  = 128*256*256;   // 8388608
    const int PAIR_N = 256*256*128;   // 8388608
    const uint32_t* probe = (const uint32_t*)d_in[2];   // row_norm_m_w = ones

    // ---- workspace layout: 70 MB ----
    char*  w     = (char*)d_ws;
    bf16*  wsts  = (bf16*)(w);                 // [0, 4MB) staged bf16 weights (GEMM ones transposed)
    float* biasF = (float*)(w + 4194304);      // [4MB, 6MB)
    bf16*  lnb   = (bf16*)(w + 6291456);       // [6MB, 22MB)
    bf16*  bufA  = (bf16*)(w + 23068672);      // [22MB, 38MB)
    bf16*  bufB  = (bf16*)(w + 39845888);      // [38MB, 54MB)
    bf16*  bufC  = (bf16*)(w + 56623104);      // [54MB, 70MB)

    float* msaF  = (float*)d_out;              // f32 msa accumulator == output 0
    float* pairF = msaF + MSA_N;               // f32 pair accumulator == output 1

    // ---- stage all weights (inputs 2..59) to bf16; GEMM weights transposed ----
    size_t woff[64]; { size_t acc = 0;
        for (int i=2;i<60;i++){ woff[i] = acc; acc += ((size_t)in_sizes[i] + 63) & ~(size_t)63; } }
    #define W(i) (wsts + woff[i])
    for (int i=2;i<60;i++){
        int tk, tn;
        if (tshape(i, tk, tn))
            cvt_wT_k<<<(in_sizes[i]+255)/256,256,0,stream>>>(d_in[i], W(i), tk, tn, probe);
        else
            cvt_w_k<<<(in_sizes[i]+255)/256,256,0,stream>>>(d_in[i], W(i), in_sizes[i], probe);
    }

    in2f_k<<<32768,256,0,stream>>>(d_in[0], msaF,  MSA_N,  probe);
    in2f_k<<<32768,256,0,stream>>>(d_in[1], pairF, PAIR_N, probe);

    #define GEMM_GRID(M,N) dim3(((N)+63)/64, (M)/64)
    #define MG(M,N)        dim3((N)/128, (M)/128)

    // ================= Row attention (bias = LN(pair)@row_bias, post-softmax) =================
    ln_k<float><<<32768,256,0,stream>>>(msaF, W(2), W(3), lnb, 256);
    ln_bias_k<<<65536,128,0,stream>>>(pairF, W(4), W(5), W(9), biasF, 8, 0);
    mgemm_k<0,0,0><<<MG(32768,256),256,0,stream>>>(lnb, W(7),        bufA, nullptr, nullptr, 32768,256,256, 256, 0,0); // Q
    mgemm_k<0,0,0><<<MG(32768,256),256,0,stream>>>(lnb, W(7)+65536,  bufB, nullptr, nullptr, 32768,256,256, 256, 0,0); // K
    mgemm_k<0,0,0><<<MG(32768,256),256,0,stream>>>(lnb, W(7)+131072, bufC, nullptr, nullptr, 32768,256,256, 256, 0,0); // V
    attn4_k<1,256><<<dim3(8,128),256,0,stream>>>(bufA, bufB, bufC, biasF, 8, 256, 1);
    mgemm_k<0,0,0><<<MG(32768,256),256,0,stream>>>(lnb, W(6), bufB, nullptr, nullptr, 32768,256,256, 256, 0,0);        // gate raw
    mulsig_k<<<32768,256,0,stream>>>(bufA, bufB, MSA_N);
    mgemm_k<0,0,1><<<MG(32768,256),256,0,stream>>>(bufA, W(8), nullptr, msaF, nullptr, 32768,256,256, 256, 0,0);

    // ================= Column attention (attend over s, L=128, no bias) =================
    ln_k<float><<<32768,256,0,stream>>>(msaF, W(10), W(11), lnb, 256);
    mgemm_k<0,0,0><<<MG(32768,256),256,0,stream>>>(lnb, W(13),        bufA, nullptr, nullptr, 32768,256,256, 256, 0,0);
    mgemm_k<0,0,0><<<MG(32768,256),256,0,stream>>>(lnb, W(13)+65536,  bufB, nullptr, nullptr, 32768,256,256, 256, 0,0);
    mgemm_k<0,0,0><<<MG(32768,256),256,0,stream>>>(lnb, W(13)+131072, bufC, nullptr, nullptr, 32768,256,256, 256, 0,0);
    attn4_k<0,128><<<dim3(8,256),256,0,stream>>>(bufA, bufB, bufC, nullptr, 8, 1, 256);
    mgemm_k<0,0,0><<<MG(32768,256),256,0,stream>>>(lnb, W(12), bufB, nullptr, nullptr, 32768,256,256, 256, 0,0);
    mulsig_k<<<32768,256,0,stream>>>(bufA, bufB, MSA_N);
    mgemm_k<0,0,1><<<MG(32768,256),256,0,stream>>>(bufA, W(14), nullptr, msaF, nullptr, 32768,256,256, 256, 0,0);

    // ================= MSA transition (FF chunked 4 x 256) =================
    ln_k<float><<<32768,256,0,stream>>>(msaF, W(15), W(16), lnb, 256);
    for (int ch=0; ch<4; ++ch){
        mgemm_k<2,0,0><<<MG(32768,256),256,0,stream>>>(lnb, W(17)+ch*65536, bufA, nullptr, nullptr, 32768,256,256, 256, 0,0);
        mgemm_k<0,0,1><<<MG(32768,256),256,0,stream>>>(bufA, W(18)+ch*256, nullptr, msaF, nullptr, 32768,256,256, 1024, 0,0);
    }

    // ================= Outer product mean (chunked 8 x 32 r's; chunks reuse lnb) =================
    ln_k<float><<<32768,256,0,stream>>>(msaF, W(19), W(20), lnb, 256);
    gemm_k<0,0,0><<<GEMM_GRID(32768,32),256,0,stream>>>(lnb, W(21), bufA, nullptr, nullptr, 32768,32,256, 32, 0,0);
    gemm_k<0,0,0><<<GEMM_GRID(32768,32),256,0,stream>>>(lnb, W(22), bufB, nullptr, nullptr, 32768,32,256, 32, 0,0);
    for (int ch=0; ch<8; ++ch){   // lnb dead; reuse as 8192x1024 chunk buffer
        outer_k<<<dim3(256,32),256,0,stream>>>(bufA, bufB, lnb, ch*32);
        mgemm_k<0,0,1><<<MG(8192,128),256,0,stream>>>(lnb, W(23), nullptr, pairF, nullptr, 8192,128,1024, 1024, ch*8192,0);
    }

    // ================= Triangle mult outgoing / incoming (MFMA batched GEMM over k) =================
    for (int tm=0; tm<2; ++tm){
        int o = tm ? 34 : 24;   // tmi_* : tmo_*
        int inc = tm;
        ln_k<float><<<65536,128,0,stream>>>(pairF, W(o+0), W(o+1), lnb, 128);
        mgemm_k<1,0,0><<<MG(65536,128),256,0,stream>>>(lnb, W(o+4), bufA, nullptr, nullptr, 65536,128,128, 128, 0,0); // sig(xn@p1)
        mgemm_k<0,1,0><<<MG(65536,128),256,0,stream>>>(lnb, W(o+5), bufA, nullptr, bufA,   65536,128,128, 128, 0,0); // a
        mgemm_k<1,0,0><<<MG(65536,128),256,0,stream>>>(lnb, W(o+6), bufB, nullptr, nullptr, 65536,128,128, 128, 0,0); // sig(xn@p3)
        mgemm_k<0,1,0><<<MG(65536,128),256,0,stream>>>(lnb, W(o+7), bufB, nullptr, bufB,   65536,128,128, 128, 0,0); // b
        rc2k_k<<<512,256,0,stream>>>(bufA, bufC, inc);                  // aT -> bufC (a dead after)
        rc2k_k<<<512,256,0,stream>>>(bufB, bufA, inc);                  // bT -> bufA (b dead after)
        btrimul_k<<<dim3(2,2,128),256,0,stream>>>(bufC, bufA, bufB);    // pT -> bufB
        k2rc_k<<<512,256,0,stream>>>(bufB, bufC);                       // p [s*256+t][k] -> bufC
        ln_k<bf16><<<65536,128,0,stream>>>(bufC, W(o+2), W(o+3), bufC, 128);  // LN(p) in place
        mgemm_k<1,0,0><<<MG(65536,128),256,0,stream>>>(lnb, W(o+9), bufA, nullptr, nullptr, 65536,128,128, 128, 0,0); // g (lnb intact)
        mgemm_k<0,1,1><<<MG(65536,128),256,0,stream>>>(bufC, W(o+8), nullptr, pairF, bufA, 65536,128,128, 128, 0, inc);
    }

    // ================= Triangle attention starting (tas) =================
    ln_k<float><<<65536,128,0,stream>>>(pairF, W(44), W(45), lnb, 128);
    ln_bias_k<<<65536,128,0,stream>>>(pairF, W(44), W(45), W(49), biasF, 4, 1);
    mgemm_k<0,0,0><<<MG(65536,128),256,0,stream>>>(lnb, W(47),       bufA, nullptr, nullptr, 65536,128,128, 128, 0,0);
    mgemm_k<0,0,0><<<MG(65536,128),256,0,stream>>>(lnb, W(47)+16384, bufB, nullptr, nullptr, 65536,128,128, 128, 0,0);
    mgemm_k<0,0,0><<<MG(65536,128),256,0,stream>>>(lnb, W(47)+32768, bufC, nullptr, nullptr, 65536,128,128, 128, 0,0);
    attn4_k<2,256><<<dim3(4,256),256,0,stream>>>(bufA, bufB, bufC, biasF, 4, 256, 1);
    mgemm_k<0,0,0><<<MG(65536,128),256,0,stream>>>(lnb, W(46), bufB, nullptr, nullptr, 65536,128,128, 128, 0,0);
    mulsig_k<<<32768,256,0,stream>>>(bufA, bufB, PAIR_N);
    mgemm_k<0,0,1><<<MG(65536,128),256,0,stream>>>(bufA, W(48), nullptr, pairF, nullptr, 65536,128,128, 128, 0,0);

    // ================= Triangle attention ending (tae) =================
    ln_k<float><<<65536,128,0,stream>>>(pairF, W(50), W(51), lnb, 128);
    ln_bias_k<<<65536,128,0,stream>>>(pairF, W(50), W(51), W(55), biasF, 4, 2);
    mgemm_k<0,0,0><<<MG(65536,128),256,0,stream>>>(lnb, W(53),       bufA, nullptr, nullptr, 65536,128,128, 128, 0,0);
    mgemm_k<0,0,0><<<MG(65536,128),256,0,stream>>>(lnb, W(53)+16384, bufB, nullptr, nullptr, 65536,128,128, 128, 0,0);
    mgemm_k<0,0,0><<<MG(65536,128),256,0,stream>>>(lnb, W(53)+32768, bufC, nullptr, nullptr, 65536,128,128, 128, 0,0);
    attn4_k<2,256><<<dim3(4,256),256,0,stream>>>(bufA, bufB, bufC, biasF, 4, 1, 256);
    mgemm_k<0,0,0><<<MG(65536,128),256,0,stream>>>(lnb, W(52), bufB, nullptr, nullptr, 65536,128,128, 128, 0,0);
    mulsig_k<<<32768,256,0,stream>>>(bufA, bufB, PAIR_N);
    mgemm_k<0,0,1><<<MG(65536,128),256,0,stream>>>(bufA, W(54), nullptr, pairF, nullptr, 65536,128,128, 128, 0,0);

    // ================= Pair transition (FF chunked 4 x 128) =================
    ln_k<float><<<65536,128,0,stream>>>(pairF, W(56), W(57), lnb, 128);
    for (int ch=0; ch<4; ++ch){
        mgemm_k<2,0,0><<<MG(65536,128),256,0,stream>>>(lnb, W(58)+ch*16384, bufA, nullptr, nullptr, 65536,128,128, 128, 0,0);
        mgemm_k<0,0,1><<<MG(65536,128),256,0,stream>>>(bufA, W(59)+ch*128, nullptr, pairF, nullptr, 65536,128,128, 512, 0,0);
    }
    // outputs are msaF/pairF in d_out (f32) — done.
}

// Round 5
// 2518.201 us; speedup vs baseline: 1.5817x; 1.0657x over previous
//
#include <hip/hip_runtime.h>
#include <hip/hip_bf16.h>
#include <stdint.h>

typedef __hip_bfloat16 bf16;
typedef __attribute__((ext_vector_type(4))) int   i32x4;
typedef __attribute__((ext_vector_type(4))) float f32x4;

// Shapes (N=1): S=128, R=256, CM=256, CZ=128, C=32, MSA_H=8, PAIR_H=4, CTM=128, FF=4
// msa rows: s*256+r (32768 x 256); pair rows: i*256+j (65536 x 128)
// I/O dtype: FLOAT32. Accumulators f32 live directly in d_out (they ARE the outputs).
// Workspace (70 MB): weights 4MB | biasF 2MB | lnb 16MB | bufA 16MB | bufB 16MB | bufC 16MB.
// GEMM weights are staged TRANSPOSED (W^T [N][K]) so MFMA B-fragments read k-contiguous bf16x8.

__device__ __forceinline__ float toF(float x){ return x; }
__device__ __forceinline__ float toF(bf16 x){ return __bfloat162float(x); }
__device__ __forceinline__ bf16  toB(float x){ return __float2bfloat16(x); }

__device__ __forceinline__ void gload16(const bf16* g, bf16* l){
    __builtin_amdgcn_global_load_lds((const __attribute__((address_space(1))) void*)g,
                                     (__attribute__((address_space(3))) void*)l, 16, 0, 0);
}

// ---------------- input staging (dtype probe: bf16 ones -> 0x3F803F80, f32 one -> 0x3F800000) ----------------
__global__ void cvt_w_k(const void* __restrict__ in, bf16* __restrict__ out, int n,
                        const uint32_t* __restrict__ probe){
    bool isbf = (probe[0] == 0x3F803F80u);
    int i = blockIdx.x*256 + threadIdx.x;
    if (i < n) out[i] = isbf ? ((const bf16*)in)[i] : toB(((const float*)in)[i]);
}
// transpose-staging for GEMM B operands: in [K][N] row-major -> out [N][K] row-major
__global__ void cvt_wT_k(const void* __restrict__ in, bf16* __restrict__ out, int K, int N,
                         const uint32_t* __restrict__ probe){
    bool isbf = (probe[0] == 0x3F803F80u);
    int i = blockIdx.x*256 + threadIdx.x;
    if (i < K*N){
        float v = isbf ? toF(((const bf16*)in)[i]) : ((const float*)in)[i];
        int k = i / N, n = i - k*N;
        out[(size_t)n*K + k] = toB(v);
    }
}
__global__ void in2f_k(const void* __restrict__ in, float* __restrict__ out, int n,
                       const uint32_t* __restrict__ probe){
    bool isbf = (probe[0] == 0x3F803F80u);
    int i = blockIdx.x*256 + threadIdx.x;
    if (i < n) out[i] = isbf ? toF(((const bf16*)in)[i]) : ((const float*)in)[i];
}

// ---------------- LayerNorm: one block per row, blockDim = D (128 or 256); in-place safe ----------------
template<typename T>
__global__ void ln_k(const T* __restrict__ x, const bf16* __restrict__ w, const bf16* __restrict__ b,
                     bf16* __restrict__ out, int D){
    int row = blockIdx.x, c = threadIdx.x;
    float v = toF(x[(size_t)row*D + c]);
    float s1 = v, s2 = v*v;
    #pragma unroll
    for (int o=32;o>0;o>>=1){ s1 += __shfl_down(s1,o); s2 += __shfl_down(s2,o); }
    __shared__ float r1[4], r2[4];
    int lane = c & 63, wid = c >> 6;
    if (lane==0){ r1[wid]=s1; r2[wid]=s2; }
    __syncthreads();
    int nw = blockDim.x >> 6;
    float m=0.f, q=0.f;
    for (int i=0;i<nw;i++){ m+=r1[i]; q+=r2[i]; }
    m /= (float)D; q = q/(float)D - m*m;
    float inv = rsqrtf(q + 1e-5f);
    out[(size_t)row*D + c] = toB((v-m)*inv*toF(w[c]) + toF(b[c]));
}

// ---------------- bias projection from bf16 LN'd pair (replaces ln_bias_k) ----------------
// value(i,j,h) = dot(xz[i*256+j], Wb[:,h]).  Layouts:
// MODE 0 (row attn, HN=8): out[h*65536 + i*256 + j]   ([h][q][k], q=i, k=j; j=t coalesced)
// MODE 1 (tas,      HN=4): out[(i*HN+h)*256 + j]      (j=t coalesced)
// MODE 2 (tae,      HN=4): out[(j*HN+h)*256 + i]      (scattered 4B writes; 1MB total, L2-merged)
template<int MODE, int HN>
__global__ __launch_bounds__(256) void bproj_k(const bf16* __restrict__ xz, const bf16* __restrict__ Wb,
                                               float* __restrict__ outb){
    __shared__ float WbS[128*HN];
    const int i = blockIdx.x, t = threadIdx.x;
    for (int idx = t; idx < 128*HN; idx += 256) WbS[idx] = toF(Wb[idx]);
    __syncthreads();
    const bf16* row = xz + ((size_t)i*256 + t)*128;
    float d[HN] = {};
    #pragma unroll 4
    for (int c8 = 0; c8 < 16; ++c8){
        uint4 v = *(const uint4*)(row + c8*8);
        bf16 tmp[8]; *(uint4*)tmp = v;
        #pragma unroll
        for (int u=0;u<8;u++){
            float x = toF(tmp[u]);
            #pragma unroll
            for (int h=0;h<HN;h++) d[h] += x * WbS[(c8*8+u)*HN + h];
        }
    }
    #pragma unroll
    for (int h=0;h<HN;h++){
        size_t idx = (MODE==0) ? ((size_t)h*65536 + (size_t)i*256 + t)
                   : (MODE==1) ? ((size_t)(i*HN+h)*256 + t)
                               : ((size_t)(t*HN+h)*256 + i);
        outb[idx] = d[h];
    }
}

// ---------------- MFMA GEMM (bf16 in, f32 accum): C[M][N] = A[M][K] @ B, B given as B^T [N][K] ----------------
template<int ACT, int MUL, int RES>
__global__ __launch_bounds__(256) void mgemm_k(const bf16* __restrict__ A, const bf16* __restrict__ Bt,
                                               bf16* __restrict__ C, float* __restrict__ Res,
                                               const bf16* __restrict__ Mul,
                                               int M, int N, int K, int ldbt, int res_off, int gtrans){
    __shared__ alignas(16) bf16 As[128*32];
    __shared__ alignas(16) bf16 Bs[128*32];
    const int tid  = threadIdx.x;
    const int m0   = blockIdx.y << 7, n0 = blockIdx.x << 7;
    const int lane = tid & 63, w = tid >> 6;
    const int wr   = (w >> 1) << 6, wc = (w & 1) << 6;
    const int fr   = lane & 15, fq = lane >> 4;
    const int sr = tid >> 2, sc = (tid & 3) << 3;
    const bf16* ga = A  + (size_t)(m0 + sr)*K    + sc;
    const bf16* gb = Bt + (size_t)(n0 + sr)*ldbt + sc;
    bf16* la = As + tid*8;
    bf16* lb = Bs + tid*8;
    const size_t gaS = (size_t)64*K, gbS = (size_t)64*ldbt;

    f32x4 acc[4][4] = {};
    for (int k0=0; k0<K; k0+=32){
        gload16(ga, la);        gload16(ga + gaS, la + 2048);
        gload16(gb, lb);        gload16(gb + gbS, lb + 2048);
        ga += 32; gb += 32;
        __syncthreads();
        i32x4 af[4], bv[4];
        #pragma unroll
        for (int i=0;i<4;i++) af[i] = *(const i32x4*)(As + ((wr + i*16 + fr) << 5) + (fq << 3));
        #pragma unroll
        for (int j=0;j<4;j++) bv[j] = *(const i32x4*)(Bs + ((wc + j*16 + fr) << 5) + (fq << 3));
        #pragma unroll
        for (int i=0;i<4;i++)
            #pragma unroll
            for (int j=0;j<4;j++)
                asm("v_mfma_f32_16x16x32_bf16 %0, %1, %2, %0"
                    : "+v"(acc[i][j]) : "v"(af[i]), "v"(bv[j]));
        __syncthreads();
    }
    #pragma unroll
    for (int i=0;i<4;i++){
        const int mB = m0 + wr + i*16 + (fq << 2);
        #pragma unroll
        for (int j=0;j<4;j++){
            const int n = n0 + wc + j*16 + fr;
            #pragma unroll
            for (int r=0;r<4;r++){
                int m = mB + r;
                float x = acc[i][j][r];
                if (ACT==1) x = 1.f/(1.f + __expf(-x));
                else if (ACT==2) x = fmaxf(x, 0.f);
                if (MUL){
                    int mr = gtrans ? (((m & 255) << 8) | (m >> 8)) : m;
                    x *= toF(Mul[(size_t)mr*N + n]);
                }
                if (RES) Res[(size_t)(m + res_off)*N + n] += x;
                else     C[(size_t)m*N + n] = toB(x);
            }
        }
    }
}

// ---------------- batched MFMA GEMM for triangle mult: per-k C_k = A_k @ B_k^T (256x256x256) ----------------
__global__ __launch_bounds__(256) void btrimul_k(const bf16* __restrict__ aT, const bf16* __restrict__ bT,
                                                 bf16* __restrict__ pT){
    __shared__ alignas(16) bf16 As[128*32];
    __shared__ alignas(16) bf16 Bs[128*32];
    const int tid  = threadIdx.x;
    const int m0   = blockIdx.y << 7, n0 = blockIdx.x << 7;
    const size_t zb = (size_t)blockIdx.z << 16;           // k*65536
    const int lane = tid & 63, w = tid >> 6;
    const int wr   = (w >> 1) << 6, wc = (w & 1) << 6;
    const int fr   = lane & 15, fq = lane >> 4;
    const int sr = tid >> 2, sc = (tid & 3) << 3;
    const bf16* ga = aT + zb + (size_t)(m0 + sr)*256 + sc;
    const bf16* gb = bT + zb + (size_t)(n0 + sr)*256 + sc;
    bf16* la = As + tid*8;
    bf16* lb = Bs + tid*8;
    const size_t gS = (size_t)64*256;

    f32x4 acc[4][4] = {};
    for (int k0=0; k0<256; k0+=32){
        gload16(ga, la);        gload16(ga + gS, la + 2048);
        gload16(gb, lb);        gload16(gb + gS, lb + 2048);
        ga += 32; gb += 32;
        __syncthreads();
        i32x4 af[4], bv[4];
        #pragma unroll
        for (int i=0;i<4;i++) af[i] = *(const i32x4*)(As + ((wr + i*16 + fr) << 5) + (fq << 3));
        #pragma unroll
        for (int j=0;j<4;j++) bv[j] = *(const i32x4*)(Bs + ((wc + j*16 + fr) << 5) + (fq << 3));
        #pragma unroll
        for (int i=0;i<4;i++)
            #pragma unroll
            for (int j=0;j<4;j++)
                asm("v_mfma_f32_16x16x32_bf16 %0, %1, %2, %0"
                    : "+v"(acc[i][j]) : "v"(af[i]), "v"(bv[j]));
        __syncthreads();
    }
    #pragma unroll
    for (int i=0;i<4;i++){
        const int mB = m0 + wr + i*16 + (fq << 2);
        #pragma unroll
        for (int j=0;j<4;j++){
            const int n = n0 + wc + j*16 + fr;
            #pragma unroll
            for (int r=0;r<4;r++)
                pT[zb + (size_t)(mB + r)*256 + n] = toB(acc[i][j][r]);
        }
    }
}

// ---------------- row/channel transposes for triangle mult ----------------
__global__ __launch_bounds__(256) void rc2k_k(const bf16* __restrict__ in, bf16* __restrict__ out, int swap){
    __shared__ uint16_t T[128][137];
    const int tt = blockIdx.x, tid = threadIdx.x;
    size_t base_pp, out_off; int ppstride;
    if (!swap){ base_pp = (size_t)tt*128;                  ppstride = 1;   out_off = (size_t)tt*128; }
    else      { int J = tt>>1, I0 = (tt&1)*128;
                base_pp = (size_t)I0*256 + J;              ppstride = 256; out_off = (size_t)J*256 + I0; }
    for (int it=0; it<8; ++it){
        int idx = tid + it*256;                 // [0,2048): 16B chunks
        int r = idx >> 4, c8 = (idx & 15) << 3;
        uint4 v = *(const uint4*)(in + (base_pp + (size_t)r*ppstride)*128 + c8);
        uint16_t tmp[8]; *(uint4*)tmp = v;
        #pragma unroll
        for (int t=0;t<8;t++) T[r][c8+t] = tmp[t];
    }
    __syncthreads();
    for (int it=0; it<8; ++it){
        int idx = tid + it*256;
        int k = idx >> 4, r8 = (idx & 15) << 3;
        uint16_t tmp[8];
        #pragma unroll
        for (int t=0;t<8;t++) tmp[t] = T[r8+t][k];
        *(uint4*)(out + (size_t)k*65536 + out_off + r8) = *(uint4*)tmp;
    }
}
__global__ __launch_bounds__(256) void k2rc_k(const bf16* __restrict__ in, bf16* __restrict__ out){
    __shared__ uint16_t T[128][137];
    const int tt = blockIdx.x, tid = threadIdx.x;
    const size_t a0 = (size_t)tt*128;
    for (int it=0; it<8; ++it){
        int idx = tid + it*256;
        int k = idx >> 4, r8 = (idx & 15) << 3;
        uint4 v = *(const uint4*)(in + (size_t)k*65536 + a0 + r8);
        uint16_t tmp[8]; *(uint4*)tmp = v;
        #pragma unroll
        for (int t=0;t<8;t++) T[r8+t][k] = tmp[t];
    }
    __syncthreads();
    for (int it=0; it<8; ++it){
        int idx = tid + it*256;
        int r = idx >> 4, c8 = (idx & 15) << 3;
        uint16_t tmp[8];
        #pragma unroll
        for (int t=0;t<8;t++) tmp[t] = T[r][c8+t];
        *(uint4*)(out + (a0 + r)*128 + c8) = *(uint4*)tmp;
    }
}

// ---------------- legacy VALU GEMM (kept only for N=32 outer projections) ----------------
template<int ACT, int MUL, int RES>
__global__ __launch_bounds__(256) void gemm_k(const bf16* __restrict__ A, const bf16* __restrict__ Bw,
                                              bf16* __restrict__ C, float* __restrict__ Res,
                                              const bf16* __restrict__ Mul,
                                              int M, int N, int K, int ldb, int res_off, int gtrans){
    __shared__ float As[64][33];
    __shared__ float Bs[32][65];
    int tid = threadIdx.x;
    int m0 = blockIdx.y*64, n0 = blockIdx.x*64;
    int tx = tid & 15, ty = tid >> 4;
    float acc[4][4] = {};
    for (int k0=0; k0<K; k0+=32){
        for (int i=tid; i<64*32; i+=256){
            int r = i>>5, cc = i&31;
            As[r][cc] = toF(A[(size_t)(m0+r)*K + k0 + cc]);
        }
        for (int i=tid; i<32*64; i+=256){
            int r = i>>6, cc = i&63; int col = n0+cc;
            Bs[r][cc] = (col < N) ? toF(Bw[(size_t)(k0+r)*ldb + col]) : 0.f;
        }
        __syncthreads();
        #pragma unroll 8
        for (int k=0;k<32;k++){
            float a4[4], b4[4];
            #pragma unroll
            for (int i=0;i<4;i++) a4[i] = As[ty*4+i][k];
            #pragma unroll
            for (int j=0;j<4;j++) b4[j] = Bs[k][tx*4+j];
            #pragma unroll
            for (int i=0;i<4;i++)
                #pragma unroll
                for (int j=0;j<4;j++) acc[i][j] += a4[i]*b4[j];
        }
        __syncthreads();
    }
    #pragma unroll
    for (int i=0;i<4;i++){
        int m = m0 + ty*4 + i;
        #pragma unroll
        for (int j=0;j<4;j++){
            int n = n0 + tx*4 + j;
            if (n >= N) continue;
            float x = acc[i][j];
            if (ACT==1) x = 1.f/(1.f + __expf(-x));
            else if (ACT==2) x = fmaxf(x, 0.f);
            if (MUL){
                int mr = gtrans ? (((m & 255) << 8) | (m >> 8)) : m;
                x *= toF(Mul[(size_t)mr*N + n]);
            }
            if (RES) Res[(size_t)(m + res_off)*N + n] += x;
            else     C[(size_t)m*N + n] = toB(x);
        }
    }
}

// ---------------- attention v4: MFMA flash attention ----------------
// One block per (h, o): 256 threads = 4 waves, wave w owns queries [w*MW, (w+1)*MW).
// K staged [L][40] bf16; V staged transposed [32][L+8]; P in wave-private LDS (no barrier in k-loop).
// Softmax without max-subtraction (scores LN-bounded) — same math as verified VALU version.
// BIAS 0: none. BIAS 1 (row attn, L=256): O += (bias@V), bias[h*65536 + q*256 + k] ([h][q][k]).
// BIAS 2 (tri attn): bias[(o*H+h)*256+k] q-uniform -> rank-1 Ob[c] computed once.
template<int BIAS, int L>
__global__ __launch_bounds__(256) void attn4_k(bf16* __restrict__ QO,
                                               const bf16* __restrict__ Kp, const bf16* __restrict__ Vp,
                                               const float* __restrict__ bias,
                                               int H, int sO, int sL){
    constexpr int MW  = L/4;       // queries per wave
    constexpr int IFR = MW/16;     // m-fragments per wave
    constexpr int KC  = 32;        // key chunk (one MFMA k-step)
    constexpr int NCH = L/KC;
    constexpr int VP  = L + 8;     // VT row pad (elems); row bytes multiple of 16
    __shared__ alignas(16) bf16 K_lds[L*40];
    __shared__ alignas(16) bf16 VT_lds[32*VP];
    __shared__ alignas(16) bf16 P_lds[L*40];      // 4 waves x MW x 40
    __shared__ float red[8*32 + 32];
    const int o = blockIdx.y, h = blockIdx.x, tid = threadIdx.x;
    const int GN = H*32;
    const int lane = tid & 63, w = tid >> 6;
    const int fr = lane & 15, fq = lane >> 4;

    // ---- stage K rows + V transposed ----
    for (int idx = tid; idx < L*4; idx += 256){
        int l = idx >> 2, c8 = (idx & 3) << 3;
        size_t p = (size_t)(o*sO + l*sL)*GN + h*32 + c8;
        *(uint4*)(K_lds + l*40 + c8) = *(const uint4*)(Kp + p);
        uint4 vv = *(const uint4*)(Vp + p);
        bf16 tmp[8]; *(uint4*)tmp = vv;
        #pragma unroll
        for (int t=0;t<8;t++) VT_lds[(c8+t)*VP + l] = tmp[t];
    }
    __syncthreads();

    float* ObS = red + 256;
    if (BIAS == 2){
        int c = tid & 31, g = tid >> 5;
        const float* bp = bias + (size_t)(o*H + h)*256;
        float p = 0.f;
        for (int k = g*(L/8); k < (g+1)*(L/8); ++k)
            p += bp[k] * toF(VT_lds[c*VP + k]);
        red[g*32 + c] = p;
        __syncthreads();
        if (tid < 32){
            float s = 0.f;
            #pragma unroll
            for (int g2=0; g2<8; ++g2) s += red[g2*32 + tid];
            ObS[tid] = s;
        }
        __syncthreads();
    }

    // ---- Q fragments (once, from global) ----
    i32x4 qf[IFR];
    #pragma unroll
    for (int i=0;i<IFR;i++){
        int q = w*MW + i*16 + fr;
        qf[i] = *(const i32x4*)(QO + (size_t)(o*sO + q*sL)*GN + h*32 + fq*8);
    }
    bf16* Pw = P_lds + w*MW*40;
    f32x4 accO[IFR][2] = {};
    f32x4 accB[IFR][2] = {};
    float lsum[IFR][4] = {};

    for (int ch=0; ch<NCH; ++ch){
        const int k0 = ch*KC;
        // S = Q @ K^T for this key chunk
        f32x4 sa[IFR][2] = {};
        i32x4 kf[2];
        #pragma unroll
        for (int j=0;j<2;j++) kf[j] = *(const i32x4*)(K_lds + (k0 + j*16 + fr)*40 + fq*8);
        #pragma unroll
        for (int i=0;i<IFR;i++)
            #pragma unroll
            for (int j=0;j<2;j++)
                asm("v_mfma_f32_16x16x32_bf16 %0, %1, %2, %0"
                    : "+v"(sa[i][j]) : "v"(qf[i]), "v"(kf[j]));
        // exp + lsum partials + write P (wave-private)
        #pragma unroll
        for (int i=0;i<IFR;i++)
            #pragma unroll
            for (int j=0;j<2;j++)
                #pragma unroll
                for (int r=0;r<4;r++){
                    float e = __expf(sa[i][j][r] * 0.17677669529663687f);
                    lsum[i][r] += e;
                    Pw[(i*16 + fq*4 + r)*40 + j*16 + fr] = toB(e);
                }
        // V^T fragments for this chunk (shared by E-PV and bias-PV)
        i32x4 vf[2];
        #pragma unroll
        for (int j=0;j<2;j++) vf[j] = *(const i32x4*)(VT_lds + (j*16 + fr)*VP + k0 + fq*8);
        // O += P @ V
        #pragma unroll
        for (int i=0;i<IFR;i++){
            i32x4 pa = *(const i32x4*)(Pw + (i*16 + fr)*40 + fq*8);
            #pragma unroll
            for (int j=0;j<2;j++)
                asm("v_mfma_f32_16x16x32_bf16 %0, %1, %2, %0"
                    : "+v"(accO[i][j]) : "v"(pa), "v"(vf[j]));
        }
        if (BIAS == 1){
            // stage this wave's bias sub-block (64 q rows x KC keys) from [h][q][k] layout
            #pragma unroll
            for (int it=0; it<32; ++it){
                int q = it*2 + (lane>>5), kk = lane&31;
                Pw[q*40 + kk] = toB(bias[(size_t)h*65536 + (size_t)(w*MW + q)*256 + k0 + kk]);
            }
            #pragma unroll
            for (int i=0;i<IFR;i++){
                i32x4 pa = *(const i32x4*)(Pw + (i*16 + fr)*40 + fq*8);
                #pragma unroll
                for (int j=0;j<2;j++)
                    asm("v_mfma_f32_16x16x32_bf16 %0, %1, %2, %0"
                        : "+v"(accB[i][j]) : "v"(pa), "v"(vf[j]));
            }
        }
    }
    // reduce lsum across the 16 fr lanes sharing each row
    #pragma unroll
    for (int i=0;i<IFR;i++)
        #pragma unroll
        for (int r=0;r<4;r++){
            float s = lsum[i][r];
            s += __shfl_xor(s, 1); s += __shfl_xor(s, 2);
            s += __shfl_xor(s, 4); s += __shfl_xor(s, 8);
            lsum[i][r] = 1.f / s;
        }
    #pragma unroll
    for (int i=0;i<IFR;i++)
        #pragma unroll
        for (int j=0;j<2;j++)
            #pragma unroll
            for (int r=0;r<4;r++){
                int q = w*MW + i*16 + fq*4 + r;
                int c = j*16 + fr;
                float v = accO[i][j][r]*lsum[i][r];
                if (BIAS==1) v += accB[i][j][r];
                if (BIAS==2) v += ObS[c];
                QO[(size_t)(o*sO + q*sL)*GN + h*32 + c] = toB(v);
            }
}

// ---------------- elementwise: a *= sigmoid(g) ----------------
__global__ void mulsig_k(bf16* __restrict__ a, const bf16* __restrict__ g, int n){
    int i = blockIdx.x*256 + threadIdx.x;
    if (i < n){
        float sg = 1.f/(1.f + __expf(-toF(g[i])));
        a[i] = toB(toF(a[i]) * sg);
    }
}

// ---------------- outer product einsum, chunked over r (32 r's per chunk) ----------------
__global__ __launch_bounds__(256) void outer_k(const bf16* __restrict__ ap, const bf16* __restrict__ bp,
                                               bf16* __restrict__ outc, int r0){
    int t = blockIdx.x, rl = blockIdx.y, r = r0 + rl;
    __shared__ float As[128*32], Bs[128*32];
    for (int idx=threadIdx.x; idx<128*32; idx+=256){
        int s = idx>>5, c = idx&31;
        As[idx] = toF(ap[((size_t)s*256 + r)*32 + c]);
        Bs[idx] = toF(bp[((size_t)s*256 + t)*32 + c]);
    }
    __syncthreads();
    int ce0 = threadIdx.x*4;
    int c = ce0 >> 5, e0 = ce0 & 31;
    float acc[4] = {0.f,0.f,0.f,0.f};
    for (int s=0;s<128;s++){
        float av = As[s*32 + c];
        #pragma unroll
        for (int j=0;j<4;j++) acc[j] += av*Bs[s*32 + e0 + j];
    }
    size_t row = (size_t)rl*256 + t;
    #pragma unroll
    for (int j=0;j<4;j++) outc[row*1024 + ce0 + j] = toB(acc[j]);
}

// ================= host =================
static bool tshape(int i, int& K, int& N){
    switch(i){
        case 6: case 8: case 12: case 14: K=256; N=256;  return true;   // msa gate/out
        case 7: case 13:                  K=256; N=768;  return true;   // msa qkv
        case 17:                          K=256; N=1024; return true;   // mt_p1
        case 18:                          K=1024;N=256;  return true;   // mt_p2
        case 23:                          K=1024;N=128;  return true;   // outer_out
        case 47: case 53:                 K=128; N=384;  return true;   // tri qkv
        case 58:                          K=128; N=512;  return true;   // pt_p1
        case 59:                          K=512; N=128;  return true;   // pt_p2
        default:
            if ((i>=28&&i<=33)||(i>=38&&i<=43)||i==46||i==48||i==52||i==54){ K=128; N=128; return true; }
            return false;
    }
}

extern "C" void kernel_launch(void* const* d_in, const int* in_sizes, int n_in,
                              void* d_out, int out_size, void* d_ws, size_t ws_size,
                              hipStream_t stream){
    (void)n_in; (void)out_size; (void)ws_size;
    const int MSA_N  = 128*256*256;   // 8388608
    const int PAIR_N = 256*256*128;   // 8388608
    const uint32_t* probe = (const uint32_t*)d_in[2];   // row_norm_m_w = ones

    // ---- workspace layout: 70 MB ----
    char*  w     = (char*)d_ws;
    bf16*  wsts  = (bf16*)(w);                 // [0, 4MB) staged bf16 weights (GEMM ones transposed)
    float* biasF = (float*)(w + 4194304);      // [4MB, 6MB)
    bf16*  lnb   = (bf16*)(w + 6291456);       // [6MB, 22MB)
    bf16*  bufA  = (bf16*)(w + 23068672);      // [22MB, 38MB)
    bf16*  bufB  = (bf16*)(w + 39845888);      // [38MB, 54MB)
    bf16*  bufC  = (bf16*)(w + 56623104);      // [54MB, 70MB)

    float* msaF  = (float*)d_out;              // f32 msa accumulator == output 0
    float* pairF = msaF + MSA_N;               // f32 pair accumulator == output 1

    // ---- stage all weights (inputs 2..59) to bf16; GEMM weights transposed ----
    size_t woff[64]; { size_t acc = 0;
        for (int i=2;i<60;i++){ woff[i] = acc; acc += ((size_t)in_sizes[i] + 63) & ~(size_t)63; } }
    #define W(i) (wsts + woff[i])
    for (int i=2;i<60;i++){
        int tk, tn;
        if (tshape(i, tk, tn))
            cvt_wT_k<<<(in_sizes[i]+255)/256,256,0,stream>>>(d_in[i], W(i), tk, tn, probe);
        else
            cvt_w_k<<<(in_sizes[i]+255)/256,256,0,stream>>>(d_in[i], W(i), in_sizes[i], probe);
    }

    in2f_k<<<32768,256,0,stream>>>(d_in[0], msaF,  MSA_N,  probe);
    in2f_k<<<32768,256,0,stream>>>(d_in[1], pairF, PAIR_N, probe);

    #define GEMM_GRID(M,N) dim3(((N)+63)/64, (M)/64)
    #define MG(M,N)        dim3((N)/128, (M)/128)

    // ================= Row attention (bias = LN_z(pair)@row_bias, post-softmax) =================
    ln_k<float><<<32768,256,0,stream>>>(msaF, W(2), W(3), lnb, 256);
    ln_k<float><<<65536,128,0,stream>>>(pairF, W(4), W(5), bufC, 128);   // xz = LN_z(pair) -> bufC (free)
    bproj_k<0,8><<<256,256,0,stream>>>(bufC, W(9), biasF);               // bias [h][q][k]
    mgemm_k<0,0,0><<<MG(32768,256),256,0,stream>>>(lnb, W(7),        bufA, nullptr, nullptr, 32768,256,256, 256, 0,0); // Q
    mgemm_k<0,0,0><<<MG(32768,256),256,0,stream>>>(lnb, W(7)+65536,  bufB, nullptr, nullptr, 32768,256,256, 256, 0,0); // K
    mgemm_k<0,0,0><<<MG(32768,256),256,0,stream>>>(lnb, W(7)+131072, bufC, nullptr, nullptr, 32768,256,256, 256, 0,0); // V
    attn4_k<1,256><<<dim3(8,128),256,0,stream>>>(bufA, bufB, bufC, biasF, 8, 256, 1);
    mgemm_k<0,0,0><<<MG(32768,256),256,0,stream>>>(lnb, W(6), bufB, nullptr, nullptr, 32768,256,256, 256, 0,0);        // gate raw
    mulsig_k<<<32768,256,0,stream>>>(bufA, bufB, MSA_N);
    mgemm_k<0,0,1><<<MG(32768,256),256,0,stream>>>(bufA, W(8), nullptr, msaF, nullptr, 32768,256,256, 256, 0,0);

    // ================= Column attention (attend over s, L=128, no bias) =================
    ln_k<float><<<32768,256,0,stream>>>(msaF, W(10), W(11), lnb, 256);
    mgemm_k<0,0,0><<<MG(32768,256),256,0,stream>>>(lnb, W(13),        bufA, nullptr, nullptr, 32768,256,256, 256, 0,0);
    mgemm_k<0,0,0><<<MG(32768,256),256,0,stream>>>(lnb, W(13)+65536,  bufB, nullptr, nullptr, 32768,256,256, 256, 0,0);
    mgemm_k<0,0,0><<<MG(32768,256),256,0,stream>>>(lnb, W(13)+131072, bufC, nullptr, nullptr, 32768,256,256, 256, 0,0);
    attn4_k<0,128><<<dim3(8,256),256,0,stream>>>(bufA, bufB, bufC, nullptr, 8, 1, 256);
    mgemm_k<0,0,0><<<MG(32768,256),256,0,stream>>>(lnb, W(12), bufB, nullptr, nullptr, 32768,256,256, 256, 0,0);
    mulsig_k<<<32768,256,0,stream>>>(bufA, bufB, MSA_N);
    mgemm_k<0,0,1><<<MG(32768,256),256,0,stream>>>(bufA, W(14), nullptr, msaF, nullptr, 32768,256,256, 256, 0,0);

    // ================= MSA transition (FF chunked 4 x 256) =================
    ln_k<float><<<32768,256,0,stream>>>(msaF, W(15), W(16), lnb, 256);
    for (int ch=0; ch<4; ++ch){
        mgemm_k<2,0,0><<<MG(32768,256),256,0,stream>>>(lnb, W(17)+ch*65536, bufA, nullptr, nullptr, 32768,256,256, 256, 0,0);
        mgemm_k<0,0,1><<<MG(32768,256),256,0,stream>>>(bufA, W(18)+ch*256, nullptr, msaF, nullptr, 32768,256,256, 1024, 0,0);
    }

    // ================= Outer product mean (chunked 8 x 32 r's; chunks reuse lnb) =================
    ln_k<float><<<32768,256,0,stream>>>(msaF, W(19), W(20), lnb, 256);
    gemm_k<0,0,0><<<GEMM_GRID(32768,32),256,0,stream>>>(lnb, W(21), bufA, nullptr, nullptr, 32768,32,256, 32, 0,0);
    gemm_k<0,0,0><<<GEMM_GRID(32768,32),256,0,stream>>>(lnb, W(22), bufB, nullptr, nullptr, 32768,32,256, 32, 0,0);
    for (int ch=0; ch<8; ++ch){   // lnb dead; reuse as 8192x1024 chunk buffer
        outer_k<<<dim3(256,32),256,0,stream>>>(bufA, bufB, lnb, ch*32);
        mgemm_k<0,0,1><<<MG(8192,128),256,0,stream>>>(lnb, W(23), nullptr, pairF, nullptr, 8192,128,1024, 1024, ch*8192,0);
    }

    // ================= Triangle mult outgoing / incoming (MFMA batched GEMM over k) =================
    for (int tm=0; tm<2; ++tm){
        int o = tm ? 34 : 24;   // tmi_* : tmo_*
        int inc = tm;
        ln_k<float><<<65536,128,0,stream>>>(pairF, W(o+0), W(o+1), lnb, 128);
        mgemm_k<1,0,0><<<MG(65536,128),256,0,stream>>>(lnb, W(o+4), bufA, nullptr, nullptr, 65536,128,128, 128, 0,0); // sig(xn@p1)
        mgemm_k<0,1,0><<<MG(65536,128),256,0,stream>>>(lnb, W(o+5), bufA, nullptr, bufA,   65536,128,128, 128, 0,0); // a
        mgemm_k<1,0,0><<<MG(65536,128),256,0,stream>>>(lnb, W(o+6), bufB, nullptr, nullptr, 65536,128,128, 128, 0,0); // sig(xn@p3)
        mgemm_k<0,1,0><<<MG(65536,128),256,0,stream>>>(lnb, W(o+7), bufB, nullptr, bufB,   65536,128,128, 128, 0,0); // b
        rc2k_k<<<512,256,0,stream>>>(bufA, bufC, inc);                  // aT -> bufC (a dead after)
        rc2k_k<<<512,256,0,stream>>>(bufB, bufA, inc);                  // bT -> bufA (b dead after)
        btrimul_k<<<dim3(2,2,128),256,0,stream>>>(bufC, bufA, bufB);    // pT -> bufB
        k2rc_k<<<512,256,0,stream>>>(bufB, bufC);                       // p [s*256+t][k] -> bufC
        ln_k<bf16><<<65536,128,0,stream>>>(bufC, W(o+2), W(o+3), bufC, 128);  // LN(p) in place
        mgemm_k<1,0,0><<<MG(65536,128),256,0,stream>>>(lnb, W(o+9), bufA, nullptr, nullptr, 65536,128,128, 128, 0,0); // g (lnb intact)
        mgemm_k<0,1,1><<<MG(65536,128),256,0,stream>>>(bufC, W(o+8), nullptr, pairF, bufA, 65536,128,128, 128, 0, inc);
    }

    // ================= Triangle attention starting (tas) =================
    ln_k<float><<<65536,128,0,stream>>>(pairF, W(44), W(45), lnb, 128);
    bproj_k<1,4><<<256,256,0,stream>>>(lnb, W(49), biasF);
    mgemm_k<0,0,0><<<MG(65536,128),256,0,stream>>>(lnb, W(47),       bufA, nullptr, nullptr, 65536,128,128, 128, 0,0);
    mgemm_k<0,0,0><<<MG(65536,128),256,0,stream>>>(lnb, W(47)+16384, bufB, nullptr, nullptr, 65536,128,128, 128, 0,0);
    mgemm_k<0,0,0><<<MG(65536,128),256,0,stream>>>(lnb, W(47)+32768, bufC, nullptr, nullptr, 65536,128,128, 128, 0,0);
    attn4_k<2,256><<<dim3(4,256),256,0,stream>>>(bufA, bufB, bufC, biasF, 4, 256, 1);
    mgemm_k<0,0,0><<<MG(65536,128),256,0,stream>>>(lnb, W(46), bufB, nullptr, nullptr, 65536,128,128, 128, 0,0);
    mulsig_k<<<32768,256,0,stream>>>(bufA, bufB, PAIR_N);
    mgemm_k<0,0,1><<<MG(65536,128),256,0,stream>>>(bufA, W(48), nullptr, pairF, nullptr, 65536,128,128, 128, 0,0);

    // ================= Triangle attention ending (tae) =================
    ln_k<float><<<65536,128,0,stream>>>(pairF, W(50), W(51), lnb, 128);
    bproj_k<2,4><<<256,256,0,stream>>>(lnb, W(55), biasF);
    mgemm_k<0,0,0><<<MG(65536,128),256,0,stream>>>(lnb, W(53),       bufA, nullptr, nullptr, 65536,128,128, 128, 0,0);
    mgemm_k<0,0,0><<<MG(65536,128),256,0,stream>>>(lnb, W(53)+16384, bufB, nullptr, nullptr, 65536,128,128, 128, 0,0);
    mgemm_k<0,0,0><<<MG(65536,128),256,0,stream>>>(lnb, W(53)+32768, bufC, nullptr, nullptr, 65536,128,128, 128, 0,0);
    attn4_k<2,256><<<dim3(4,256),256,0,stream>>>(bufA, bufB, bufC, biasF, 4, 1, 256);
    mgemm_k<0,0,0><<<MG(65536,128),256,0,stream>>>(lnb, W(52), bufB, nullptr, nullptr, 65536,128,128, 128, 0,0);
    mulsig_k<<<32768,256,0,stream>>>(bufA, bufB, PAIR_N);
    mgemm_k<0,0,1><<<MG(65536,128),256,0,stream>>>(bufA, W(54), nullptr, pairF, nullptr, 65536,128,128, 128, 0,0);

    // ================= Pair transition (FF chunked 4 x 128) =================
    ln_k<float><<<65536,128,0,stream>>>(pairF, W(56), W(57), lnb, 128);
    for (int ch=0; ch<4; ++ch){
        mgemm_k<2,0,0><<<MG(65536,128),256,0,stream>>>(lnb, W(58)+ch*16384, bufA, nullptr, nullptr, 65536,128,128, 128, 0,0);
        mgemm_k<0,0,1><<<MG(65536,128),256,0,stream>>>(bufA, W(59)+ch*128, nullptr, pairF, nullptr, 65536,128,128, 512, 0,0);
    }
    // outputs are msaF/pairF in d_out (f32) — done.
}